// Round 14
// baseline (435.155 us; speedup 1.0000x reference)
//
#include <hip/hip_runtime.h>
#include <stdint.h>

#define NN 50000   // nodes
#define NE 600000  // edges
#define NG 1000    // graphs
#define AD 64      // input feat
#define HD 128     // hidden
#define OD 256     // output
#define BN_EPS_F 1e-5f
#define INV_N (1.0f / 50000.0f)
#define NB 196     // scan blocks = ceil(NN/256)
#define FILLB 293  // fill tail blocks (8 edges/thread)
#define DEGB 586   // degree tail blocks (4 edges/thread)
#define PREWB 416  // prew main blocks (wt convert = 106496 threads)
#define NCOPY 32   // stats spread copies (256 floats each)
#define SREG (NCOPY * 256)  // floats per stat region
#define SADJ 768   // LDS-staged adj entries per gather block

typedef __attribute__((ext_vector_type(8))) short  mbf16x8;
typedef __attribute__((ext_vector_type(4))) float  mf32x4;
typedef __attribute__((ext_vector_type(4))) unsigned short mu16x4;
typedef __attribute__((ext_vector_type(4))) unsigned int   mu32x4;

__device__ __forceinline__ float bf2f(unsigned short u) {
    union { unsigned int i; float f; } v; v.i = ((unsigned int)u) << 16; return v.f;
}
__device__ __forceinline__ unsigned short f2bf(float f) {
    union { float f; unsigned int i; } v; v.f = f;
    unsigned int r = v.i + 0x7fffu + ((v.i >> 16) & 1u);  // RNE
    return (unsigned short)(r >> 16);
}
// BN (scale, shift) for column c from folded raw sums
__device__ __forceinline__ void bn_ss(
    const float* stats, const float* __restrict__ gamma,
    const float* __restrict__ beta, int c, float& sc, float& sh)
{
    const float mean = stats[c] * INV_N;
    const float var = fmaxf(stats[128 + c] * INV_N - mean * mean, 0.f);
    const float inv = rsqrtf(var + BN_EPS_F);
    sc = gamma[c] * inv;
    sh = beta[c] - mean * sc;
}
// fold 32 spread copies of stat index t (t < 256) from a region
__device__ __forceinline__ float fold_stat(const float* __restrict__ reg, int t)
{
    float a = 0.f;
#pragma unroll
    for (int c = 0; c < NCOPY; c++) a += reg[c * 256 + t];
    return a;
}

// ---------------------------------------------------------------------------
// prew: wt[n][k] bf16 from W[k][n] fp32 (PREWB blocks) + zero stats.
// Tail blocks (DEGB): degree histogram (4 edges/thread). deg pre-zeroed.
// ---------------------------------------------------------------------------
__global__ __launch_bounds__(256) void prew_kernel(
    const float* __restrict__ emb_W, const float* __restrict__ W1,
    const float* __restrict__ W2, unsigned short* __restrict__ wt,
    float* __restrict__ stats, const int* __restrict__ ei,
    int* __restrict__ deg)
{
    if ((int)blockIdx.x >= PREWB) {
        const int e0 = ((blockIdx.x - PREWB) * 256 + threadIdx.x) * 4;
        if (e0 < NE) {   // NE % 4 == 0
            const int4 rv = *(const int4*)(ei + e0);
            if ((unsigned)rv.x < NN) atomicAdd(&deg[rv.x], 1);
            if ((unsigned)rv.y < NN) atomicAdd(&deg[rv.y], 1);
            if ((unsigned)rv.z < NN) atomicAdd(&deg[rv.z], 1);
            if ((unsigned)rv.w < NN) atomicAdd(&deg[rv.w], 1);
        }
        return;
    }
    const int t = blockIdx.x * 256 + threadIdx.x;
    if (t < 6 * SREG) stats[t] = 0.f;
    if (t < 8192) {                    // emb: n=t>>6, k=t&63
        wt[t] = f2bf(emb_W[(t & 63) * 128 + (t >> 6)]);
    } else {
        const int t2 = t - 8192;
        if (t2 >= 6 * 16384) return;
        const int which = t2 >> 14, o = t2 & 16383;
        const int n = o >> 7, k = o & 127;
        const float* src = (which < 3) ? (W1 + (size_t)which * 16384)
                                       : (W2 + (size_t)(which - 3) * 16384);
        wt[t] = f2bf(src[k * 128 + n]);
    }
}

// ---------------------------------------------------------------------------
// GEMM: out_bf16[N,128] = A[N,K] @ Wt^T + bias   (B direct from global)
// RG row-groups/wave (tile rows = RG*64); B-frag loads shared across RG.
// AMODE: 0 = A fp32, 1 = A bf16 plain, 2 = A bf16 with BN(stats_in)+ReLU
// SOUT:  per-column sum/sumsq -> spread copy (bid&31); consumers fold.
// TAIL:  1 = CSR fill tail blocks (8 edges/thread), 2 = graph-starts tail
// ---------------------------------------------------------------------------
template <int K, int RG, int AMODE, bool SOUT, int TAIL>
__global__ __launch_bounds__(256) void gemm_kernel(
    const void* __restrict__ in, const unsigned short* __restrict__ Wt,
    const float* __restrict__ bias, const float* __restrict__ stats_in,
    const float* __restrict__ gamma, const float* __restrict__ beta,
    unsigned short* __restrict__ out, float* __restrict__ stats_out, int n_rows,
    const int* __restrict__ t_a, int* __restrict__ t_b, int* __restrict__ t_c)
{
    constexpr int TAILB = (TAIL == 1) ? FILLB : (TAIL == 2) ? NB : 0;
    if (TAIL != 0 && (int)blockIdx.x < TAILB) {
        const int t = blockIdx.x * 256 + threadIdx.x;
        if constexpr (TAIL == 1) {
            const int e0 = t * 8;
            if (e0 < NE) {   // NE % 8 == 0
                const int4 r0 = *(const int4*)(t_a + e0);
                const int4 r1 = *(const int4*)(t_a + e0 + 4);
                const int4 c0 = *(const int4*)(t_a + NE + e0);
                const int4 c1 = *(const int4*)(t_a + NE + e0 + 4);
                if ((unsigned)r0.x < NN && (unsigned)c0.x < NN)
                    t_c[atomicAdd(&t_b[r0.x], 1)] = c0.x;
                if ((unsigned)r0.y < NN && (unsigned)c0.y < NN)
                    t_c[atomicAdd(&t_b[r0.y], 1)] = c0.y;
                if ((unsigned)r0.z < NN && (unsigned)c0.z < NN)
                    t_c[atomicAdd(&t_b[r0.z], 1)] = c0.z;
                if ((unsigned)r0.w < NN && (unsigned)c0.w < NN)
                    t_c[atomicAdd(&t_b[r0.w], 1)] = c0.w;
                if ((unsigned)r1.x < NN && (unsigned)c1.x < NN)
                    t_c[atomicAdd(&t_b[r1.x], 1)] = c1.x;
                if ((unsigned)r1.y < NN && (unsigned)c1.y < NN)
                    t_c[atomicAdd(&t_b[r1.y], 1)] = c1.y;
                if ((unsigned)r1.z < NN && (unsigned)c1.z < NN)
                    t_c[atomicAdd(&t_b[r1.z], 1)] = c1.z;
                if ((unsigned)r1.w < NN && (unsigned)c1.w < NN)
                    t_c[atomicAdd(&t_b[r1.w], 1)] = c1.w;
            }
        } else {  // TAIL == 2: graph starts
            if (t < NN) {
                int b = t_a[t];
                int pb = (t == 0) ? -1 : t_a[t - 1];
                if (b > NG - 1) b = NG - 1;
                if (pb > NG - 1) pb = NG - 1;
                for (int g = pb + 1; g <= b; g++) t_b[g] = t;
                if (t == NN - 1)
                    for (int g = b + 1; g <= NG; g++) t_b[g] = NN;
            }
        }
        return;
    }
    const int bid = blockIdx.x - TAILB;

    constexpr int ROWS = RG * 64;
    constexpr int SA = K + 8;
    __shared__ unsigned short zs[ROWS * SA];
    __shared__ float ssl[128], ssh[128];
    __shared__ float lsum[128], lsq[128];
    __shared__ float sarr[256];

    const int tid = threadIdx.x;
    const int wave = tid >> 6, lane = tid & 63;
    const int row0 = bid * ROWS;

    if (SOUT && tid < 128) { lsum[tid] = 0.f; lsq[tid] = 0.f; }
    if (AMODE == 2) {
        sarr[tid] = fold_stat(stats_in, tid);
        __syncthreads();
        if (tid < 128) {
            float sc, sh; bn_ss(sarr, gamma, beta, tid, sc, sh);
            ssl[tid] = sc; ssh[tid] = sh;
        }
        __syncthreads();
    }

    // ---- stage A tile -> LDS ----
    if constexpr (AMODE == 0) {
        const float* src = (const float*)in;
        constexpr int LPR = K / 4;
        for (int i = tid; i < ROWS * LPR; i += 256) {
            const int r = i / LPR, c4 = (i % LPR) * 4;
            mf32x4 v = {0.f, 0.f, 0.f, 0.f};
            if (row0 + r < n_rows)
                v = *(const mf32x4*)(src + (size_t)(row0 + r) * K + c4);
            mu16x4 o;
            o[0] = f2bf(v[0]); o[1] = f2bf(v[1]); o[2] = f2bf(v[2]); o[3] = f2bf(v[3]);
            *(mu16x4*)(&zs[r * SA + c4]) = o;
        }
    } else {
        const unsigned short* src = (const unsigned short*)in;
        constexpr int LPR = K / 8;
        float sc[8], sh[8];
        if constexpr (AMODE == 2) {
            const int c8 = (tid % LPR) * 8;   // fixed per thread (256 % LPR == 0)
#pragma unroll
            for (int j = 0; j < 8; j++) { sc[j] = ssl[c8 + j]; sh[j] = ssh[c8 + j]; }
        }
        for (int i = tid; i < ROWS * LPR; i += 256) {
            const int r = i / LPR, c8 = (i % LPR) * 8;
            mu32x4 v = {0, 0, 0, 0};
            if (row0 + r < n_rows)
                v = *(const mu32x4*)(src + (size_t)(row0 + r) * K + c8);
            if constexpr (AMODE == 2) {
                const unsigned short* u = (const unsigned short*)&v;
                mu16x4 oa, ob;
#pragma unroll
                for (int j = 0; j < 4; j++)
                    oa[j] = f2bf(fmaxf(bf2f(u[j]) * sc[j] + sh[j], 0.f));
#pragma unroll
                for (int j = 0; j < 4; j++)
                    ob[j] = f2bf(fmaxf(bf2f(u[4 + j]) * sc[4 + j] + sh[4 + j], 0.f));
                *(mu16x4*)(&zs[r * SA + c8]) = oa;
                *(mu16x4*)(&zs[r * SA + c8 + 4]) = ob;
            } else {
                *(mu32x4*)(&zs[r * SA + c8]) = v;
            }
        }
    }
    __syncthreads();

    // ---- MFMA: B-frags direct from global, shared across RG row-groups ----
    mf32x4 acc[RG][8];
#pragma unroll
    for (int g = 0; g < RG; g++)
#pragma unroll
        for (int t = 0; t < 8; t++) acc[g][t] = {0.f, 0.f, 0.f, 0.f};
    const int kq = (lane >> 4) * 8;
    int mrow[RG];
#pragma unroll
    for (int g = 0; g < RG; g++) mrow[g] = wave * (16 * RG) + g * 16 + (lane & 15);
    const unsigned short* wn = Wt + (lane & 15) * K;  // + t*16*K + k0
#pragma unroll 1
    for (int kk = 0; kk < K / 32; kk++) {
        const int k0 = kk * 32 + kq;
        mbf16x8 a[RG];
#pragma unroll
        for (int g = 0; g < RG; g++) a[g] = *(const mbf16x8*)(&zs[mrow[g] * SA + k0]);
        mbf16x8 bfr[8];
#pragma unroll
        for (int t = 0; t < 8; t++) bfr[t] = *(const mbf16x8*)(wn + t * 16 * K + k0);
#pragma unroll
        for (int t = 0; t < 8; t++)
#pragma unroll
            for (int g = 0; g < RG; g++)
                acc[g][t] = __builtin_amdgcn_mfma_f32_16x16x32_bf16(
                    a[g], bfr[t], acc[g][t], 0, 0, 0);
    }

    // ---- epilogue: +bias, store bf16; stats -> spread copy (bid&31) ----
#pragma unroll
    for (int g = 0; g < RG; g++) {
        const int rbase = wave * (16 * RG) + g * 16 + ((lane >> 4) << 2);
#pragma unroll
        for (int t = 0; t < 8; t++) {
            const int c = t * 16 + (lane & 15);
            const float bv = bias[c];
            float s = 0.f, q = 0.f;
#pragma unroll
            for (int r = 0; r < 4; r++) {
                const int grow = row0 + rbase + r;
                const float y = acc[g][t][r] + bv;
                if (grow < n_rows) {
                    out[(size_t)grow * 128 + c] = f2bf(y);
                    if (SOUT) { s += y; q += y * y; }
                }
            }
            if (SOUT) {
                s += __shfl_xor(s, 16); s += __shfl_xor(s, 32);
                q += __shfl_xor(q, 16); q += __shfl_xor(q, 32);
                if ((lane >> 4) == 0) {
                    atomicAdd(&lsum[c], s);
                    atomicAdd(&lsq[c], q);
                }
            }
        }
    }
    if (SOUT) {
        __syncthreads();
        float* cb = stats_out + (bid & (NCOPY - 1)) * 256;
        if (tid < 128) {
            atomicAdd(&cb[tid], lsum[tid]);
            atomicAdd(&cb[128 + tid], lsq[tid]);
        }
    }
}

// ---------------------------------------------------------------------------
// CSR build: bscan -> scanfix  (deg done in prew tail)
// ---------------------------------------------------------------------------
__global__ __launch_bounds__(256) void bscan_kernel(
    const int* __restrict__ deg, int* __restrict__ rowptr, int* __restrict__ bsum)
{
    __shared__ int sm[256];
    const int t = threadIdx.x, idx = blockIdx.x * 256 + t;
    const int d = (idx < NN) ? deg[idx] : 0;
    sm[t] = d; __syncthreads();
    for (int ofs = 1; ofs < 256; ofs <<= 1) {
        int v = (t >= ofs) ? sm[t - ofs] : 0;
        __syncthreads();
        sm[t] += v;
        __syncthreads();
    }
    if (idx < NN) rowptr[idx] = sm[t] - d;  // exclusive, block-local
    if (t == 255) bsum[blockIdx.x] = sm[255];
}

__global__ __launch_bounds__(256) void scanfix_kernel(
    const int* __restrict__ bsum, int* __restrict__ rowptr, int* __restrict__ cursor)
{
    __shared__ int sm[256];
    const int t = threadIdx.x;
    const int d = (t < NB) ? bsum[t] : 0;
    sm[t] = d; __syncthreads();
    for (int ofs = 1; ofs < 256; ofs <<= 1) {
        int v = (t >= ofs) ? sm[t - ofs] : 0;
        __syncthreads();
        sm[t] += v;
        __syncthreads();
    }
    const int boff = (blockIdx.x == 0) ? 0 : sm[blockIdx.x - 1];
    const int idx = blockIdx.x * 256 + t;
    if (idx < NN) {
        const int v = rowptr[idx] + boff;
        rowptr[idx] = v;
        cursor[idx] = v;
    }
    if (blockIdx.x == NB - 1 && t == 0) rowptr[NN] = sm[NB - 1];
}

// ---------------------------------------------------------------------------
// gather: z[n] = (1+eps[l])*f(src[n]) + sum_{c in adj[n]} f(src[c])
// 16 nodes/block; block's contiguous adj segment staged to LDS (coalesced);
// 8-deep independent neighbor-load pipeline.
// ---------------------------------------------------------------------------
template <bool BN>
__global__ __launch_bounds__(256) void gather_kernel(
    const unsigned short* __restrict__ src, const int* __restrict__ rowptr,
    const int* __restrict__ adj, const float* __restrict__ stats,
    const float* __restrict__ gamma, const float* __restrict__ beta,
    const float* __restrict__ eps, int l, unsigned short* __restrict__ z)
{
    __shared__ float sarr[256];
    __shared__ int srp[17];
    __shared__ int sadj[SADJ];
    const int tid = threadIdx.x;
    if constexpr (BN) sarr[tid] = fold_stat(stats, tid);
    const int n0 = blockIdx.x * 16;
    if (tid < 17) srp[tid] = rowptr[n0 + tid];
    __syncthreads();
    const int base = srp[0];
    const int total = srp[16] - base;
    for (int i = tid; i < total && i < SADJ; i += 256) sadj[i] = adj[base + i];
    __syncthreads();

    const int node = n0 + (tid >> 4);
    const int c0 = (tid & 15) * 8;
    float sc[8], sh[8];
    if (BN) {
#pragma unroll
        for (int j = 0; j < 8; j++) bn_ss(sarr, gamma, beta, c0 + j, sc[j], sh[j]);
    }
    const float e1 = 1.0f + eps[l];
    float acc[8];
    {
        mu32x4 v = *(const mu32x4*)(src + (size_t)node * HD + c0);
        const unsigned short* u = (const unsigned short*)&v;
#pragma unroll
        for (int j = 0; j < 8; j++) {
            float f = bf2f(u[j]);
            if (BN) f = fmaxf(f * sc[j] + sh[j], 0.f);
            acc[j] = e1 * f;
        }
    }
    const int s = srp[tid >> 4] - base;
    const int e = srp[(tid >> 4) + 1] - base;
    auto nb_at = [&](int i) -> int {
        return (i < SADJ) ? sadj[i] : adj[base + i];
    };
    int i = s;
    for (; i + 8 <= e; i += 8) {   // 8 independent 16B loads in flight
        mu32x4 v[8];
#pragma unroll
        for (int k = 0; k < 8; k++)
            v[k] = *(const mu32x4*)(src + (size_t)nb_at(i + k) * HD + c0);
#pragma unroll
        for (int k = 0; k < 8; k++) {
            const unsigned short* u = (const unsigned short*)&v[k];
#pragma unroll
            for (int j = 0; j < 8; j++) {
                float f = bf2f(u[j]);
                if (BN) f = fmaxf(f * sc[j] + sh[j], 0.f);
                acc[j] += f;
            }
        }
    }
    if (i + 4 <= e) {
        mu32x4 v[4];
#pragma unroll
        for (int k = 0; k < 4; k++)
            v[k] = *(const mu32x4*)(src + (size_t)nb_at(i + k) * HD + c0);
#pragma unroll
        for (int k = 0; k < 4; k++) {
            const unsigned short* u = (const unsigned short*)&v[k];
#pragma unroll
            for (int j = 0; j < 8; j++) {
                float f = bf2f(u[j]);
                if (BN) f = fmaxf(f * sc[j] + sh[j], 0.f);
                acc[j] += f;
            }
        }
        i += 4;
    }
    for (; i < e; i++) {
        mu32x4 v = *(const mu32x4*)(src + (size_t)nb_at(i) * HD + c0);
        const unsigned short* u = (const unsigned short*)&v;
#pragma unroll
        for (int j = 0; j < 8; j++) {
            float f = bf2f(u[j]);
            if (BN) f = fmaxf(f * sc[j] + sh[j], 0.f);
            acc[j] += f;
        }
    }
    mu16x4 o0, o1;
#pragma unroll
    for (int j = 0; j < 4; j++) o0[j] = f2bf(acc[j]);
#pragma unroll
    for (int j = 0; j < 4; j++) o1[j] = f2bf(acc[4 + j]);
    *(mu16x4*)(z + (size_t)node * HD + c0) = o0;
    *(mu16x4*)(z + (size_t)node * HD + c0 + 4) = o1;
}

// ---------------------------------------------------------------------------
// pooled[g] = sum over graph rows of BN+ReLU(y); then out[g] = pooled @ pw + pb
// ---------------------------------------------------------------------------
__global__ __launch_bounds__(256) void poolfinal_kernel(
    const unsigned short* __restrict__ y, const int* __restrict__ start,
    const float* __restrict__ stats, const float* __restrict__ gamma,
    const float* __restrict__ beta, const float* __restrict__ pw,
    const float* __restrict__ pb, float* __restrict__ out)
{
    __shared__ float red[16][128];
    __shared__ float pl[128];
    __shared__ float sarr[256];
    sarr[threadIdx.x] = fold_stat(stats, threadIdx.x);
    __syncthreads();
    const int g = blockIdx.x;
    const int rg = threadIdx.x >> 4;
    const int c0 = (threadIdx.x & 15) * 8;
    float sc[8], sh[8];
#pragma unroll
    for (int j = 0; j < 8; j++) bn_ss(sarr, gamma, beta, c0 + j, sc[j], sh[j]);
    int s = start[g], e = start[g + 1];
    if (s < 0) s = 0;
    if (e > NN) e = NN;
    float acc[8];
#pragma unroll
    for (int j = 0; j < 8; j++) acc[j] = 0.f;
    for (int n = s + rg; n < e; n += 16) {
        mu32x4 v = *(const mu32x4*)(y + (size_t)n * HD + c0);
        const unsigned short* u = (const unsigned short*)&v;
#pragma unroll
        for (int j = 0; j < 8; j++)
            acc[j] += fmaxf(bf2f(u[j]) * sc[j] + sh[j], 0.f);
    }
#pragma unroll
    for (int j = 0; j < 8; j++) red[rg][c0 + j] = acc[j];
    __syncthreads();
    if (threadIdx.x < 128) {
        float a = 0.f;
#pragma unroll
        for (int k = 0; k < 16; k++) a += red[k][threadIdx.x];
        pl[threadIdx.x] = a;
    }
    __syncthreads();
    const int o = threadIdx.x;
    float facc = pb[o];
#pragma unroll 4
    for (int k = 0; k < 128; k++) facc += pl[k] * pw[k * 256 + o];
    out[(size_t)g * 256 + o] = facc;
}

// ---------------------------------------------------------------------------
extern "C" void kernel_launch(void* const* d_in, const int* in_sizes, int n_in,
                              void* d_out, int out_size, void* d_ws, size_t ws_size,
                              hipStream_t stream)
{
    const float* x      = (const float*)d_in[0];
    const int*   edge   = (const int*)d_in[1];
    const int*   batch  = (const int*)d_in[2];
    const float* emb_W  = (const float*)d_in[4];
    const float* emb_b  = (const float*)d_in[5];
    const float* W1     = (const float*)d_in[6];
    const float* b1     = (const float*)d_in[7];
    const float* g1     = (const float*)d_in[8];
    const float* be1    = (const float*)d_in[9];
    const float* W2     = (const float*)d_in[10];
    const float* b2     = (const float*)d_in[11];
    const float* g2     = (const float*)d_in[12];
    const float* be2    = (const float*)d_in[13];
    const float* eps    = (const float*)d_in[14];
    const float* proj_W = (const float*)d_in[15];
    const float* proj_b = (const float*)d_in[16];
    float* out = (float*)d_out;

    char* ws = (char*)d_ws;
    size_t off = 0;
    auto take = [&](size_t bytes) -> char* {
        char* p = ws + off;
        off += (bytes + 255) & ~(size_t)255;
        return p;
    };
    float*          stats  = (float*)take(6 * SREG * 4);   // 196 KB
    int*            start  = (int*)take((NG + 1) * 4);
    int*            deg    = (int*)take(NN * 4);
    int*            rowptr = (int*)take((NN + 1) * 4);
    int*            cursor = (int*)take(NN * 4);
    int*            bsum   = (int*)take(256 * 4);
    unsigned short* wt     = (unsigned short*)take((size_t)(8192 + 6 * 16384) * 2);
    int*            adj    = (int*)take((size_t)NE * 4);
    unsigned short* zbuf   = (unsigned short*)take((size_t)NN * HD * 2);
    unsigned short* y1buf  = (unsigned short*)take((size_t)NN * HD * 2);
    unsigned short* y2buf  = (unsigned short*)take((size_t)NN * HD * 2);

    const int eg_grid = (NN + 127) / 128;  // 391 (embed, RG=2)
    const int lg_grid = (NN + 127) / 128;  // 391 (layer GEMMs, RG=2)
    auto st = [&](int r) { return stats + (size_t)r * SREG; };

    hipMemsetAsync(deg, 0, NN * 4, stream);
    // packed: wt convert + stats zero (416 blocks) || degree histogram (586)
    prew_kernel<<<PREWB + DEGB, 256, 0, stream>>>(
        emb_W, W1, W2, wt, stats, edge, deg);
    bscan_kernel<<<NB, 256, 0, stream>>>(deg, rowptr, bsum);
    scanfix_kernel<<<NB, 256, 0, stream>>>(bsum, rowptr, cursor);

    // packed: CSR fill (293 blocks, 8 edges/thread) || embed GEMM (391, RG=2)
    gemm_kernel<AD, 2, 0, false, 1><<<FILLB + eg_grid, 256, 0, stream>>>(
        x, wt, emb_b, nullptr, nullptr, nullptr, y2buf, nullptr, NN,
        edge, cursor, adj);

    for (int l = 0; l < 3; l++) {
        if (l == 0)
            gather_kernel<false><<<(NN + 15) / 16, 256, 0, stream>>>(
                y2buf, rowptr, adj, nullptr, nullptr, nullptr, eps, l, zbuf);
        else
            gather_kernel<true><<<(NN + 15) / 16, 256, 0, stream>>>(
                y2buf, rowptr, adj, st(2 * l - 1),
                g2 + (l - 1) * HD, be2 + (l - 1) * HD, eps, l, zbuf);
        gemm_kernel<HD, 2, 1, true, 0><<<lg_grid, 256, 0, stream>>>(
            zbuf, wt + 8192 + (size_t)l * 16384, b1 + l * HD,
            nullptr, nullptr, nullptr, y1buf, st(2 * l), NN,
            nullptr, nullptr, nullptr);
        if (l < 2)
            gemm_kernel<HD, 2, 2, true, 0><<<lg_grid, 256, 0, stream>>>(
                y1buf, wt + 8192 + (size_t)(3 + l) * 16384, b2 + l * HD,
                st(2 * l), g1 + l * HD, be1 + l * HD, y2buf, st(2 * l + 1), NN,
                nullptr, nullptr, nullptr);
        else
            // packed: graph starts (196 blocks) || last GEMM2 (391 blocks)
            gemm_kernel<HD, 2, 2, true, 2><<<NB + lg_grid, 256, 0, stream>>>(
                y1buf, wt + 8192 + (size_t)(3 + l) * 16384, b2 + l * HD,
                st(2 * l), g1 + l * HD, be1 + l * HD, y2buf, st(2 * l + 1), NN,
                batch, start, nullptr);
    }

    poolfinal_kernel<<<NG, 256, 0, stream>>>(
        y2buf, start, st(5), g2 + 2 * HD, be2 + 2 * HD, proj_W, proj_b, out);
}

// Round 15
// 385.304 us; speedup vs baseline: 1.1294x; 1.1294x over previous
//
#include <hip/hip_runtime.h>
#include <stdint.h>

#define NN 50000   // nodes
#define NE 600000  // edges
#define NG 1000    // graphs
#define AD 64      // input feat
#define HD 128     // hidden
#define OD 256     // output
#define BN_EPS_F 1e-5f
#define INV_N (1.0f / 50000.0f)
#define NB 196     // scan blocks = ceil(NN/256)
#define FILLB 586  // fill tail blocks (4 edges/thread, pure stores)
#define DEGB 586   // degree tail blocks (4 edges/thread, eoff capture)
#define PREWB 416  // prew main blocks (wt convert = 106496 threads)
#define NCOPY 32   // stats spread copies (256 floats each)
#define SREG (NCOPY * 256)  // floats per stat region

typedef __attribute__((ext_vector_type(8))) short  mbf16x8;
typedef __attribute__((ext_vector_type(4))) float  mf32x4;
typedef __attribute__((ext_vector_type(4))) unsigned short mu16x4;
typedef __attribute__((ext_vector_type(4))) unsigned int   mu32x4;

__device__ __forceinline__ float bf2f(unsigned short u) {
    union { unsigned int i; float f; } v; v.i = ((unsigned int)u) << 16; return v.f;
}
__device__ __forceinline__ unsigned short f2bf(float f) {
    union { float f; unsigned int i; } v; v.f = f;
    unsigned int r = v.i + 0x7fffu + ((v.i >> 16) & 1u);  // RNE
    return (unsigned short)(r >> 16);
}
// BN (scale, shift) for column c from folded raw sums
__device__ __forceinline__ void bn_ss(
    const float* stats, const float* __restrict__ gamma,
    const float* __restrict__ beta, int c, float& sc, float& sh)
{
    const float mean = stats[c] * INV_N;
    const float var = fmaxf(stats[128 + c] * INV_N - mean * mean, 0.f);
    const float inv = rsqrtf(var + BN_EPS_F);
    sc = gamma[c] * inv;
    sh = beta[c] - mean * sc;
}
// fold 32 spread copies of stat index t (t < 256) from a region
__device__ __forceinline__ float fold_stat(const float* __restrict__ reg, int t)
{
    float a = 0.f;
#pragma unroll
    for (int c = 0; c < NCOPY; c++) a += reg[c * 256 + t];
    return a;
}

// ---------------------------------------------------------------------------
// prew: wt[n][k] bf16 from W[k][n] fp32 (PREWB blocks) + zero stats.
// Tail blocks (DEGB): degree histogram, capturing each edge's within-row
// slot (eoff[e] = old count) so the fill pass needs NO atomics.
// ---------------------------------------------------------------------------
__global__ __launch_bounds__(256) void prew_kernel(
    const float* __restrict__ emb_W, const float* __restrict__ W1,
    const float* __restrict__ W2, unsigned short* __restrict__ wt,
    float* __restrict__ stats, const int* __restrict__ ei,
    int* __restrict__ deg, int* __restrict__ eoff)
{
    if ((int)blockIdx.x >= PREWB) {
        const int e0 = ((blockIdx.x - PREWB) * 256 + threadIdx.x) * 4;
        if (e0 < NE) {   // NE % 4 == 0
            const int4 rv = *(const int4*)(ei + e0);
            int4 off = {0, 0, 0, 0};
            if ((unsigned)rv.x < NN) off.x = atomicAdd(&deg[rv.x], 1);
            if ((unsigned)rv.y < NN) off.y = atomicAdd(&deg[rv.y], 1);
            if ((unsigned)rv.z < NN) off.z = atomicAdd(&deg[rv.z], 1);
            if ((unsigned)rv.w < NN) off.w = atomicAdd(&deg[rv.w], 1);
            *(int4*)(eoff + e0) = off;
        }
        return;
    }
    const int t = blockIdx.x * 256 + threadIdx.x;
    if (t < 6 * SREG) stats[t] = 0.f;
    if (t < 8192) {                    // emb: n=t>>6, k=t&63
        wt[t] = f2bf(emb_W[(t & 63) * 128 + (t >> 6)]);
    } else {
        const int t2 = t - 8192;
        if (t2 >= 6 * 16384) return;
        const int which = t2 >> 14, o = t2 & 16383;
        const int n = o >> 7, k = o & 127;
        const float* src = (which < 3) ? (W1 + (size_t)which * 16384)
                                       : (W2 + (size_t)(which - 3) * 16384);
        wt[t] = f2bf(src[k * 128 + n]);
    }
}

// ---------------------------------------------------------------------------
// GEMM: out_bf16[N,128] = A[N,K] @ Wt^T + bias   (B direct from global)
// RG row-groups/wave (tile rows = RG*64); B-frag loads shared across RG.
// AMODE: 0 = A fp32, 1 = A bf16 plain, 2 = A bf16 with BN(stats_in)+ReLU
// SOUT:  per-column sum/sumsq -> spread copy (bid&31); consumers fold.
// TAIL:  1 = CSR fill tail (pure stores: adj[rowptr[r]+eoff[e]] = c)
//        2 = graph-starts tail
// ---------------------------------------------------------------------------
template <int K, int RG, int AMODE, bool SOUT, int TAIL>
__global__ __launch_bounds__(256) void gemm_kernel(
    const void* __restrict__ in, const unsigned short* __restrict__ Wt,
    const float* __restrict__ bias, const float* __restrict__ stats_in,
    const float* __restrict__ gamma, const float* __restrict__ beta,
    unsigned short* __restrict__ out, float* __restrict__ stats_out, int n_rows,
    const int* __restrict__ t_a, int* __restrict__ t_b, int* __restrict__ t_c,
    const int* __restrict__ t_d)
{
    constexpr int TAILB = (TAIL == 1) ? FILLB : (TAIL == 2) ? NB : 0;
    if (TAIL != 0 && (int)blockIdx.x < TAILB) {
        const int t = blockIdx.x * 256 + threadIdx.x;
        if constexpr (TAIL == 1) {
            // t_a = edge, t_b = rowptr (read-only), t_c = adj, t_d = eoff
            const int e0 = t * 4;
            if (e0 < NE) {   // NE % 4 == 0
                const int4 rv = *(const int4*)(t_a + e0);
                const int4 cv = *(const int4*)(t_a + NE + e0);
                const int4 ov = *(const int4*)(t_d + e0);
                if ((unsigned)rv.x < NN && (unsigned)cv.x < NN)
                    t_c[t_b[rv.x] + ov.x] = cv.x;
                if ((unsigned)rv.y < NN && (unsigned)cv.y < NN)
                    t_c[t_b[rv.y] + ov.y] = cv.y;
                if ((unsigned)rv.z < NN && (unsigned)cv.z < NN)
                    t_c[t_b[rv.z] + ov.z] = cv.z;
                if ((unsigned)rv.w < NN && (unsigned)cv.w < NN)
                    t_c[t_b[rv.w] + ov.w] = cv.w;
            }
        } else {  // TAIL == 2: graph starts
            if (t < NN) {
                int b = t_a[t];
                int pb = (t == 0) ? -1 : t_a[t - 1];
                if (b > NG - 1) b = NG - 1;
                if (pb > NG - 1) pb = NG - 1;
                for (int g = pb + 1; g <= b; g++) t_b[g] = t;
                if (t == NN - 1)
                    for (int g = b + 1; g <= NG; g++) t_b[g] = NN;
            }
        }
        return;
    }
    const int bid = blockIdx.x - TAILB;

    constexpr int ROWS = RG * 64;
    constexpr int SA = K + 8;
    __shared__ unsigned short zs[ROWS * SA];
    __shared__ float ssl[128], ssh[128];
    __shared__ float lsum[128], lsq[128];
    __shared__ float sarr[256];

    const int tid = threadIdx.x;
    const int wave = tid >> 6, lane = tid & 63;
    const int row0 = bid * ROWS;

    if (SOUT && tid < 128) { lsum[tid] = 0.f; lsq[tid] = 0.f; }
    if (AMODE == 2) {
        sarr[tid] = fold_stat(stats_in, tid);
        __syncthreads();
        if (tid < 128) {
            float sc, sh; bn_ss(sarr, gamma, beta, tid, sc, sh);
            ssl[tid] = sc; ssh[tid] = sh;
        }
        __syncthreads();
    }

    // ---- stage A tile -> LDS ----
    if constexpr (AMODE == 0) {
        const float* src = (const float*)in;
        constexpr int LPR = K / 4;
        for (int i = tid; i < ROWS * LPR; i += 256) {
            const int r = i / LPR, c4 = (i % LPR) * 4;
            mf32x4 v = {0.f, 0.f, 0.f, 0.f};
            if (row0 + r < n_rows)
                v = *(const mf32x4*)(src + (size_t)(row0 + r) * K + c4);
            mu16x4 o;
            o[0] = f2bf(v[0]); o[1] = f2bf(v[1]); o[2] = f2bf(v[2]); o[3] = f2bf(v[3]);
            *(mu16x4*)(&zs[r * SA + c4]) = o;
        }
    } else {
        const unsigned short* src = (const unsigned short*)in;
        constexpr int LPR = K / 8;
        float sc[8], sh[8];
        if constexpr (AMODE == 2) {
            const int c8 = (tid % LPR) * 8;   // fixed per thread (256 % LPR == 0)
#pragma unroll
            for (int j = 0; j < 8; j++) { sc[j] = ssl[c8 + j]; sh[j] = ssh[c8 + j]; }
        }
        for (int i = tid; i < ROWS * LPR; i += 256) {
            const int r = i / LPR, c8 = (i % LPR) * 8;
            mu32x4 v = {0, 0, 0, 0};
            if (row0 + r < n_rows)
                v = *(const mu32x4*)(src + (size_t)(row0 + r) * K + c8);
            if constexpr (AMODE == 2) {
                const unsigned short* u = (const unsigned short*)&v;
                mu16x4 oa, ob;
#pragma unroll
                for (int j = 0; j < 4; j++)
                    oa[j] = f2bf(fmaxf(bf2f(u[j]) * sc[j] + sh[j], 0.f));
#pragma unroll
                for (int j = 0; j < 4; j++)
                    ob[j] = f2bf(fmaxf(bf2f(u[4 + j]) * sc[4 + j] + sh[4 + j], 0.f));
                *(mu16x4*)(&zs[r * SA + c8]) = oa;
                *(mu16x4*)(&zs[r * SA + c8 + 4]) = ob;
            } else {
                *(mu32x4*)(&zs[r * SA + c8]) = v;
            }
        }
    }
    __syncthreads();

    // ---- MFMA: B-frags direct from global, shared across RG row-groups ----
    mf32x4 acc[RG][8];
#pragma unroll
    for (int g = 0; g < RG; g++)
#pragma unroll
        for (int t = 0; t < 8; t++) acc[g][t] = {0.f, 0.f, 0.f, 0.f};
    const int kq = (lane >> 4) * 8;
    int mrow[RG];
#pragma unroll
    for (int g = 0; g < RG; g++) mrow[g] = wave * (16 * RG) + g * 16 + (lane & 15);
    const unsigned short* wn = Wt + (lane & 15) * K;  // + t*16*K + k0
#pragma unroll 1
    for (int kk = 0; kk < K / 32; kk++) {
        const int k0 = kk * 32 + kq;
        mbf16x8 a[RG];
#pragma unroll
        for (int g = 0; g < RG; g++) a[g] = *(const mbf16x8*)(&zs[mrow[g] * SA + k0]);
        mbf16x8 bfr[8];
#pragma unroll
        for (int t = 0; t < 8; t++) bfr[t] = *(const mbf16x8*)(wn + t * 16 * K + k0);
#pragma unroll
        for (int t = 0; t < 8; t++)
#pragma unroll
            for (int g = 0; g < RG; g++)
                acc[g][t] = __builtin_amdgcn_mfma_f32_16x16x32_bf16(
                    a[g], bfr[t], acc[g][t], 0, 0, 0);
    }

    // ---- epilogue: +bias, store bf16; stats -> spread copy (bid&31) ----
#pragma unroll
    for (int g = 0; g < RG; g++) {
        const int rbase = wave * (16 * RG) + g * 16 + ((lane >> 4) << 2);
#pragma unroll
        for (int t = 0; t < 8; t++) {
            const int c = t * 16 + (lane & 15);
            const float bv = bias[c];
            float s = 0.f, q = 0.f;
#pragma unroll
            for (int r = 0; r < 4; r++) {
                const int grow = row0 + rbase + r;
                const float y = acc[g][t][r] + bv;
                if (grow < n_rows) {
                    out[(size_t)grow * 128 + c] = f2bf(y);
                    if (SOUT) { s += y; q += y * y; }
                }
            }
            if (SOUT) {
                s += __shfl_xor(s, 16); s += __shfl_xor(s, 32);
                q += __shfl_xor(q, 16); q += __shfl_xor(q, 32);
                if ((lane >> 4) == 0) {
                    atomicAdd(&lsum[c], s);
                    atomicAdd(&lsq[c], q);
                }
            }
        }
    }
    if (SOUT) {
        __syncthreads();
        float* cb = stats_out + (bid & (NCOPY - 1)) * 256;
        if (tid < 128) {
            atomicAdd(&cb[tid], lsum[tid]);
            atomicAdd(&cb[128 + tid], lsq[tid]);
        }
    }
}

// ---------------------------------------------------------------------------
// CSR build: bscan -> scanfix  (deg+eoff done in prew tail; no cursor)
// ---------------------------------------------------------------------------
__global__ __launch_bounds__(256) void bscan_kernel(
    const int* __restrict__ deg, int* __restrict__ rowptr, int* __restrict__ bsum)
{
    __shared__ int sm[256];
    const int t = threadIdx.x, idx = blockIdx.x * 256 + t;
    const int d = (idx < NN) ? deg[idx] : 0;
    sm[t] = d; __syncthreads();
    for (int ofs = 1; ofs < 256; ofs <<= 1) {
        int v = (t >= ofs) ? sm[t - ofs] : 0;
        __syncthreads();
        sm[t] += v;
        __syncthreads();
    }
    if (idx < NN) rowptr[idx] = sm[t] - d;  // exclusive, block-local
    if (t == 255) bsum[blockIdx.x] = sm[255];
}

__global__ __launch_bounds__(256) void scanfix_kernel(
    const int* __restrict__ bsum, int* __restrict__ rowptr)
{
    __shared__ int sm[256];
    const int t = threadIdx.x;
    const int d = (t < NB) ? bsum[t] : 0;
    sm[t] = d; __syncthreads();
    for (int ofs = 1; ofs < 256; ofs <<= 1) {
        int v = (t >= ofs) ? sm[t - ofs] : 0;
        __syncthreads();
        sm[t] += v;
        __syncthreads();
    }
    const int boff = (blockIdx.x == 0) ? 0 : sm[blockIdx.x - 1];
    const int idx = blockIdx.x * 256 + t;
    if (idx < NN) rowptr[idx] += boff;
    if (blockIdx.x == NB - 1 && t == 0) rowptr[NN] = sm[NB - 1];
}

// ---------------------------------------------------------------------------
// gather: z[n] = (1+eps[l])*f(src[n]) + sum_{c in adj[n]} f(src[c])
// 16 threads/node x 16B loads; 16 nodes per 256-thread block; 4-deep unroll.
// (r13 form: VGPR ~12, high occupancy — TLP beats ILP here, r14 lesson)
// ---------------------------------------------------------------------------
template <bool BN>
__global__ __launch_bounds__(256) void gather_kernel(
    const unsigned short* __restrict__ src, const int* __restrict__ rowptr,
    const int* __restrict__ adj, const float* __restrict__ stats,
    const float* __restrict__ gamma, const float* __restrict__ beta,
    const float* __restrict__ eps, int l, unsigned short* __restrict__ z)
{
    __shared__ float sarr[256];
    if constexpr (BN) {
        sarr[threadIdx.x] = fold_stat(stats, threadIdx.x);
        __syncthreads();
    }
    const int node = blockIdx.x * 16 + (threadIdx.x >> 4);
    const int c0 = (threadIdx.x & 15) * 8;
    if (node >= NN) return;
    float sc[8], sh[8];
    if (BN) {
#pragma unroll
        for (int j = 0; j < 8; j++) bn_ss(sarr, gamma, beta, c0 + j, sc[j], sh[j]);
    }
    const float e = 1.0f + eps[l];
    float acc[8];
    {
        mu32x4 v = *(const mu32x4*)(src + (size_t)node * HD + c0);
        const unsigned short* u = (const unsigned short*)&v;
#pragma unroll
        for (int j = 0; j < 8; j++) {
            float f = bf2f(u[j]);
            if (BN) f = fmaxf(f * sc[j] + sh[j], 0.f);
            acc[j] = e * f;
        }
    }
    const int s = rowptr[node], t = rowptr[node + 1];
    int i = s;
    for (; i + 4 <= t; i += 4) {
        const int n0 = adj[i], n1 = adj[i + 1], n2 = adj[i + 2], n3 = adj[i + 3];
        mu32x4 v0 = *(const mu32x4*)(src + (size_t)n0 * HD + c0);
        mu32x4 v1 = *(const mu32x4*)(src + (size_t)n1 * HD + c0);
        mu32x4 v2 = *(const mu32x4*)(src + (size_t)n2 * HD + c0);
        mu32x4 v3 = *(const mu32x4*)(src + (size_t)n3 * HD + c0);
        const unsigned short* u0 = (const unsigned short*)&v0;
        const unsigned short* u1 = (const unsigned short*)&v1;
        const unsigned short* u2 = (const unsigned short*)&v2;
        const unsigned short* u3 = (const unsigned short*)&v3;
#pragma unroll
        for (int j = 0; j < 8; j++) {
            float f0 = bf2f(u0[j]), f1 = bf2f(u1[j]);
            float f2 = bf2f(u2[j]), f3 = bf2f(u3[j]);
            if (BN) {
                f0 = fmaxf(f0 * sc[j] + sh[j], 0.f);
                f1 = fmaxf(f1 * sc[j] + sh[j], 0.f);
                f2 = fmaxf(f2 * sc[j] + sh[j], 0.f);
                f3 = fmaxf(f3 * sc[j] + sh[j], 0.f);
            }
            acc[j] += (f0 + f1) + (f2 + f3);
        }
    }
    for (; i < t; i++) {
        mu32x4 v = *(const mu32x4*)(src + (size_t)adj[i] * HD + c0);
        const unsigned short* u = (const unsigned short*)&v;
#pragma unroll
        for (int j = 0; j < 8; j++) {
            float f = bf2f(u[j]);
            if (BN) f = fmaxf(f * sc[j] + sh[j], 0.f);
            acc[j] += f;
        }
    }
    mu16x4 o0, o1;
#pragma unroll
    for (int j = 0; j < 4; j++) o0[j] = f2bf(acc[j]);
#pragma unroll
    for (int j = 0; j < 4; j++) o1[j] = f2bf(acc[4 + j]);
    *(mu16x4*)(z + (size_t)node * HD + c0) = o0;
    *(mu16x4*)(z + (size_t)node * HD + c0 + 4) = o1;
}

// ---------------------------------------------------------------------------
// pooled[g] = sum over graph rows of BN+ReLU(y); then out[g] = pooled @ pw + pb
// ---------------------------------------------------------------------------
__global__ __launch_bounds__(256) void poolfinal_kernel(
    const unsigned short* __restrict__ y, const int* __restrict__ start,
    const float* __restrict__ stats, const float* __restrict__ gamma,
    const float* __restrict__ beta, const float* __restrict__ pw,
    const float* __restrict__ pb, float* __restrict__ out)
{
    __shared__ float red[16][128];
    __shared__ float pl[128];
    __shared__ float sarr[256];
    sarr[threadIdx.x] = fold_stat(stats, threadIdx.x);
    __syncthreads();
    const int g = blockIdx.x;
    const int rg = threadIdx.x >> 4;
    const int c0 = (threadIdx.x & 15) * 8;
    float sc[8], sh[8];
#pragma unroll
    for (int j = 0; j < 8; j++) bn_ss(sarr, gamma, beta, c0 + j, sc[j], sh[j]);
    int s = start[g], e = start[g + 1];
    if (s < 0) s = 0;
    if (e > NN) e = NN;
    float acc[8];
#pragma unroll
    for (int j = 0; j < 8; j++) acc[j] = 0.f;
    for (int n = s + rg; n < e; n += 16) {
        mu32x4 v = *(const mu32x4*)(y + (size_t)n * HD + c0);
        const unsigned short* u = (const unsigned short*)&v;
#pragma unroll
        for (int j = 0; j < 8; j++)
            acc[j] += fmaxf(bf2f(u[j]) * sc[j] + sh[j], 0.f);
    }
#pragma unroll
    for (int j = 0; j < 8; j++) red[rg][c0 + j] = acc[j];
    __syncthreads();
    if (threadIdx.x < 128) {
        float a = 0.f;
#pragma unroll
        for (int k = 0; k < 16; k++) a += red[k][threadIdx.x];
        pl[threadIdx.x] = a;
    }
    __syncthreads();
    const int o = threadIdx.x;
    float facc = pb[o];
#pragma unroll 4
    for (int k = 0; k < 128; k++) facc += pl[k] * pw[k * 256 + o];
    out[(size_t)g * 256 + o] = facc;
}

// ---------------------------------------------------------------------------
extern "C" void kernel_launch(void* const* d_in, const int* in_sizes, int n_in,
                              void* d_out, int out_size, void* d_ws, size_t ws_size,
                              hipStream_t stream)
{
    const float* x      = (const float*)d_in[0];
    const int*   edge   = (const int*)d_in[1];
    const int*   batch  = (const int*)d_in[2];
    const float* emb_W  = (const float*)d_in[4];
    const float* emb_b  = (const float*)d_in[5];
    const float* W1     = (const float*)d_in[6];
    const float* b1     = (const float*)d_in[7];
    const float* g1     = (const float*)d_in[8];
    const float* be1    = (const float*)d_in[9];
    const float* W2     = (const float*)d_in[10];
    const float* b2     = (const float*)d_in[11];
    const float* g2     = (const float*)d_in[12];
    const float* be2    = (const float*)d_in[13];
    const float* eps    = (const float*)d_in[14];
    const float* proj_W = (const float*)d_in[15];
    const float* proj_b = (const float*)d_in[16];
    float* out = (float*)d_out;

    char* ws = (char*)d_ws;
    size_t off = 0;
    auto take = [&](size_t bytes) -> char* {
        char* p = ws + off;
        off += (bytes + 255) & ~(size_t)255;
        return p;
    };
    float*          stats  = (float*)take(6 * SREG * 4);   // 196 KB
    int*            start  = (int*)take((NG + 1) * 4);
    int*            deg    = (int*)take(NN * 4);
    int*            rowptr = (int*)take((NN + 1) * 4);
    int*            bsum   = (int*)take(256 * 4);
    unsigned short* wt     = (unsigned short*)take((size_t)(8192 + 6 * 16384) * 2);
    int*            adj    = (int*)take((size_t)NE * 4);
    int*            eoff   = (int*)take((size_t)NE * 4);
    unsigned short* zbuf   = (unsigned short*)take((size_t)NN * HD * 2);
    unsigned short* y1buf  = (unsigned short*)take((size_t)NN * HD * 2);
    unsigned short* y2buf  = (unsigned short*)take((size_t)NN * HD * 2);

    const int eg_grid = (NN + 63) / 64;    // 782 (embed, RG=1)
    const int lg_grid = (NN + 127) / 128;  // 391 (layer GEMMs, RG=2)
    auto st = [&](int r) { return stats + (size_t)r * SREG; };

    hipMemsetAsync(deg, 0, NN * 4, stream);
    // packed: wt convert + stats zero (416 blocks) || deg histogram + eoff (586)
    prew_kernel<<<PREWB + DEGB, 256, 0, stream>>>(
        emb_W, W1, W2, wt, stats, edge, deg, eoff);
    bscan_kernel<<<NB, 256, 0, stream>>>(deg, rowptr, bsum);
    scanfix_kernel<<<NB, 256, 0, stream>>>(bsum, rowptr);

    // packed: CSR fill, atomic-free (586 blocks) || embed GEMM (782, RG=1)
    gemm_kernel<AD, 1, 0, false, 1><<<FILLB + eg_grid, 256, 0, stream>>>(
        x, wt, emb_b, nullptr, nullptr, nullptr, y2buf, nullptr, NN,
        edge, rowptr, adj, eoff);

    for (int l = 0; l < 3; l++) {
        if (l == 0)
            gather_kernel<false><<<(NN + 15) / 16, 256, 0, stream>>>(
                y2buf, rowptr, adj, nullptr, nullptr, nullptr, eps, l, zbuf);
        else
            gather_kernel<true><<<(NN + 15) / 16, 256, 0, stream>>>(
                y2buf, rowptr, adj, st(2 * l - 1),
                g2 + (l - 1) * HD, be2 + (l - 1) * HD, eps, l, zbuf);
        gemm_kernel<HD, 2, 1, true, 0><<<lg_grid, 256, 0, stream>>>(
            zbuf, wt + 8192 + (size_t)l * 16384, b1 + l * HD,
            nullptr, nullptr, nullptr, y1buf, st(2 * l), NN,
            nullptr, nullptr, nullptr, nullptr);
        if (l < 2)
            gemm_kernel<HD, 2, 2, true, 0><<<lg_grid, 256, 0, stream>>>(
                y1buf, wt + 8192 + (size_t)(3 + l) * 16384, b2 + l * HD,
                st(2 * l), g1 + l * HD, be1 + l * HD, y2buf, st(2 * l + 1), NN,
                nullptr, nullptr, nullptr, nullptr);
        else
            // packed: graph starts (196 blocks) || last GEMM2 (391 blocks)
            gemm_kernel<HD, 2, 2, true, 2><<<NB + lg_grid, 256, 0, stream>>>(
                y1buf, wt + 8192 + (size_t)(3 + l) * 16384, b2 + l * HD,
                st(2 * l), g1 + l * HD, be1 + l * HD, y2buf, st(2 * l + 1), NN,
                batch, start, nullptr, nullptr);
    }

    poolfinal_kernel<<<NG, 256, 0, stream>>>(
        y2buf, start, st(5), g2 + 2 * HD, be2 + 2 * HD, proj_W, proj_b, out);
}

// Round 16
// 379.999 us; speedup vs baseline: 1.1451x; 1.0140x over previous
//
#include <hip/hip_runtime.h>
#include <stdint.h>

#define NN 50000   // nodes
#define NE 600000  // edges
#define NG 1000    // graphs
#define AD 64      // input feat
#define HD 128     // hidden
#define OD 256     // output
#define BN_EPS_F 1e-5f
#define INV_N (1.0f / 50000.0f)
#define NB 196     // scan blocks = ceil(NN/256)
#define FILLB 586  // fill tail blocks (4 edges/thread, pure stores)
#define DEGB 586   // degree tail blocks (4 edges/thread, eoff capture)
#define PREWB 416  // prew main blocks (wt convert = 106496 threads)
#define NCOPY 32   // stats spread copies (256 floats each)
#define SREG (NCOPY * 256)  // floats per stat region

typedef __attribute__((ext_vector_type(8))) short  mbf16x8;
typedef __attribute__((ext_vector_type(4))) float  mf32x4;
typedef __attribute__((ext_vector_type(4))) unsigned short mu16x4;
typedef __attribute__((ext_vector_type(4))) unsigned int   mu32x4;

union frag_cast { mu32x4 u; mbf16x8 b; mu16x4 h[2]; };

__device__ __forceinline__ float bf2f(unsigned short u) {
    union { unsigned int i; float f; } v; v.i = ((unsigned int)u) << 16; return v.f;
}
__device__ __forceinline__ unsigned short f2bf(float f) {
    union { float f; unsigned int i; } v; v.f = f;
    unsigned int r = v.i + 0x7fffu + ((v.i >> 16) & 1u);  // RNE
    return (unsigned short)(r >> 16);
}
// BN (scale, shift) for column c from folded raw sums
__device__ __forceinline__ void bn_ss(
    const float* stats, const float* __restrict__ gamma,
    const float* __restrict__ beta, int c, float& sc, float& sh)
{
    const float mean = stats[c] * INV_N;
    const float var = fmaxf(stats[128 + c] * INV_N - mean * mean, 0.f);
    const float inv = rsqrtf(var + BN_EPS_F);
    sc = gamma[c] * inv;
    sh = beta[c] - mean * sc;
}
// fold 32 spread copies of stat index t (t < 256) from a region
__device__ __forceinline__ float fold_stat(const float* __restrict__ reg, int t)
{
    float a = 0.f;
#pragma unroll
    for (int c = 0; c < NCOPY; c++) a += reg[c * 256 + t];
    return a;
}

// ---------------------------------------------------------------------------
// prew: wt[n][k] bf16 from W[k][n] fp32 (PREWB blocks) + zero stats.
// Tail blocks (DEGB): degree histogram, capturing each edge's within-row
// slot (eoff[e] = old count) so the fill pass needs NO atomics.
// ---------------------------------------------------------------------------
__global__ __launch_bounds__(256) void prew_kernel(
    const float* __restrict__ emb_W, const float* __restrict__ W1,
    const float* __restrict__ W2, unsigned short* __restrict__ wt,
    float* __restrict__ stats, const int* __restrict__ ei,
    int* __restrict__ deg, int* __restrict__ eoff)
{
    if ((int)blockIdx.x >= PREWB) {
        const int e0 = ((blockIdx.x - PREWB) * 256 + threadIdx.x) * 4;
        if (e0 < NE) {   // NE % 4 == 0
            const int4 rv = *(const int4*)(ei + e0);
            int4 off = {0, 0, 0, 0};
            if ((unsigned)rv.x < NN) off.x = atomicAdd(&deg[rv.x], 1);
            if ((unsigned)rv.y < NN) off.y = atomicAdd(&deg[rv.y], 1);
            if ((unsigned)rv.z < NN) off.z = atomicAdd(&deg[rv.z], 1);
            if ((unsigned)rv.w < NN) off.w = atomicAdd(&deg[rv.w], 1);
            *(int4*)(eoff + e0) = off;
        }
        return;
    }
    const int t = blockIdx.x * 256 + threadIdx.x;
    if (t < 6 * SREG) stats[t] = 0.f;
    if (t < 8192) {                    // emb: n=t>>6, k=t&63
        wt[t] = f2bf(emb_W[(t & 63) * 128 + (t >> 6)]);
    } else {
        const int t2 = t - 8192;
        if (t2 >= 6 * 16384) return;
        const int which = t2 >> 14, o = t2 & 16383;
        const int n = o >> 7, k = o & 127;
        const float* src = (which < 3) ? (W1 + (size_t)which * 16384)
                                       : (W2 + (size_t)(which - 3) * 16384);
        wt[t] = f2bf(src[k * 128 + n]);
    }
}

// ---------------------------------------------------------------------------
// GEMM: out_bf16[N,128] = A[N,K] @ Wt^T + bias
// AMODE 0: A fp32 -> LDS staging (embed; packed under fill)
// AMODE 1/2: A bf16 loaded DIRECTLY global->registers in the k-loop —
//   A has zero reuse within a block, so LDS staging was pure overhead
//   (35 KB LDS + 2 barrier drains). AMODE 2 applies BN+ReLU in registers.
// SOUT: per-column sum/sumsq -> spread copy (bid&31); consumers fold.
// TAIL: 1 = CSR fill tail (pure stores), 2 = graph-starts tail
// ---------------------------------------------------------------------------
template <int K, int RG, int AMODE, bool SOUT, int TAIL>
__global__ __launch_bounds__(256) void gemm_kernel(
    const void* __restrict__ in, const unsigned short* __restrict__ Wt,
    const float* __restrict__ bias, const float* __restrict__ stats_in,
    const float* __restrict__ gamma, const float* __restrict__ beta,
    unsigned short* __restrict__ out, float* __restrict__ stats_out, int n_rows,
    const int* __restrict__ t_a, int* __restrict__ t_b, int* __restrict__ t_c,
    const int* __restrict__ t_d)
{
    constexpr int TAILB = (TAIL == 1) ? FILLB : (TAIL == 2) ? NB : 0;
    if (TAIL != 0 && (int)blockIdx.x < TAILB) {
        const int t = blockIdx.x * 256 + threadIdx.x;
        if constexpr (TAIL == 1) {
            // t_a = edge, t_b = rowptr (read-only), t_c = adj, t_d = eoff
            const int e0 = t * 4;
            if (e0 < NE) {   // NE % 4 == 0
                const int4 rv = *(const int4*)(t_a + e0);
                const int4 cv = *(const int4*)(t_a + NE + e0);
                const int4 ov = *(const int4*)(t_d + e0);
                if ((unsigned)rv.x < NN && (unsigned)cv.x < NN)
                    t_c[t_b[rv.x] + ov.x] = cv.x;
                if ((unsigned)rv.y < NN && (unsigned)cv.y < NN)
                    t_c[t_b[rv.y] + ov.y] = cv.y;
                if ((unsigned)rv.z < NN && (unsigned)cv.z < NN)
                    t_c[t_b[rv.z] + ov.z] = cv.z;
                if ((unsigned)rv.w < NN && (unsigned)cv.w < NN)
                    t_c[t_b[rv.w] + ov.w] = cv.w;
            }
        } else {  // TAIL == 2: graph starts
            if (t < NN) {
                int b = t_a[t];
                int pb = (t == 0) ? -1 : t_a[t - 1];
                if (b > NG - 1) b = NG - 1;
                if (pb > NG - 1) pb = NG - 1;
                for (int g = pb + 1; g <= b; g++) t_b[g] = t;
                if (t == NN - 1)
                    for (int g = b + 1; g <= NG; g++) t_b[g] = NN;
            }
        }
        return;
    }
    const int bid = blockIdx.x - TAILB;

    constexpr int ROWS = RG * 64;
    constexpr int SA = K + 8;
    constexpr int ZN = (AMODE == 0) ? ROWS * SA : 1;
    __shared__ unsigned short zs[ZN];
    __shared__ float ssl[128], ssh[128];
    __shared__ float lsum[128], lsq[128];
    __shared__ float sarr[256];

    const int tid = threadIdx.x;
    const int wave = tid >> 6, lane = tid & 63;
    const int row0 = bid * ROWS;

    if (SOUT && tid < 128) { lsum[tid] = 0.f; lsq[tid] = 0.f; }
    if (AMODE == 2) {
        sarr[tid] = fold_stat(stats_in, tid);
        __syncthreads();
        if (tid < 128) {
            float sc, sh; bn_ss(sarr, gamma, beta, tid, sc, sh);
            ssl[tid] = sc; ssh[tid] = sh;
        }
        __syncthreads();
    }

    // ---- AMODE 0 only: stage fp32 A tile -> LDS ----
    if constexpr (AMODE == 0) {
        const float* src = (const float*)in;
        constexpr int LPR = K / 4;
        for (int i = tid; i < ROWS * LPR; i += 256) {
            const int r = i / LPR, c4 = (i % LPR) * 4;
            mf32x4 v = {0.f, 0.f, 0.f, 0.f};
            if (row0 + r < n_rows)
                v = *(const mf32x4*)(src + (size_t)(row0 + r) * K + c4);
            mu16x4 o;
            o[0] = f2bf(v[0]); o[1] = f2bf(v[1]); o[2] = f2bf(v[2]); o[3] = f2bf(v[3]);
            *(mu16x4*)(&zs[r * SA + c4]) = o;
        }
        __syncthreads();
    }

    // ---- MFMA: B-frags from global; A-frags from LDS (0) or global (1/2) ----
    mf32x4 acc[RG][8];
#pragma unroll
    for (int g = 0; g < RG; g++)
#pragma unroll
        for (int t = 0; t < 8; t++) acc[g][t] = {0.f, 0.f, 0.f, 0.f};
    const int kq = (lane >> 4) * 8;
    int mrow[RG];
#pragma unroll
    for (int g = 0; g < RG; g++) mrow[g] = wave * (16 * RG) + g * 16 + (lane & 15);
    const unsigned short* asrc = (const unsigned short*)in;
    const unsigned short* wn = Wt + (lane & 15) * K;  // + t*16*K + k0
#pragma unroll 1
    for (int kk = 0; kk < K / 32; kk++) {
        const int k0 = kk * 32 + kq;
        mbf16x8 a[RG];
        if constexpr (AMODE == 0) {
#pragma unroll
            for (int g = 0; g < RG; g++)
                a[g] = *(const mbf16x8*)(&zs[mrow[g] * SA + k0]);
        } else {
#pragma unroll
            for (int g = 0; g < RG; g++) {
                frag_cast fc;
                fc.u = (mu32x4){0, 0, 0, 0};
                const int grow = row0 + mrow[g];
                if (grow < n_rows)
                    fc.u = *(const mu32x4*)(asrc + (size_t)grow * K + k0);
                if constexpr (AMODE == 2) {
                    const mf32x4 sc0 = *(const mf32x4*)(ssl + k0);
                    const mf32x4 sc1 = *(const mf32x4*)(ssl + k0 + 4);
                    const mf32x4 sh0 = *(const mf32x4*)(ssh + k0);
                    const mf32x4 sh1 = *(const mf32x4*)(ssh + k0 + 4);
                    const unsigned short* u = (const unsigned short*)&fc.u;
                    mu16x4 pa, pb2;
#pragma unroll
                    for (int j = 0; j < 4; j++)
                        pa[j] = f2bf(fmaxf(bf2f(u[j]) * sc0[j] + sh0[j], 0.f));
#pragma unroll
                    for (int j = 0; j < 4; j++)
                        pb2[j] = f2bf(fmaxf(bf2f(u[4 + j]) * sc1[j] + sh1[j], 0.f));
                    fc.h[0] = pa; fc.h[1] = pb2;
                }
                a[g] = fc.b;
            }
        }
        mbf16x8 bfr[8];
#pragma unroll
        for (int t = 0; t < 8; t++) bfr[t] = *(const mbf16x8*)(wn + t * 16 * K + k0);
#pragma unroll
        for (int t = 0; t < 8; t++)
#pragma unroll
            for (int g = 0; g < RG; g++)
                acc[g][t] = __builtin_amdgcn_mfma_f32_16x16x32_bf16(
                    a[g], bfr[t], acc[g][t], 0, 0, 0);
    }

    // ---- epilogue: +bias, store bf16; stats -> spread copy (bid&31) ----
#pragma unroll
    for (int g = 0; g < RG; g++) {
        const int rbase = wave * (16 * RG) + g * 16 + ((lane >> 4) << 2);
#pragma unroll
        for (int t = 0; t < 8; t++) {
            const int c = t * 16 + (lane & 15);
            const float bv = bias[c];
            float s = 0.f, q = 0.f;
#pragma unroll
            for (int r = 0; r < 4; r++) {
                const int grow = row0 + rbase + r;
                const float y = acc[g][t][r] + bv;
                if (grow < n_rows) {
                    out[(size_t)grow * 128 + c] = f2bf(y);
                    if (SOUT) { s += y; q += y * y; }
                }
            }
            if (SOUT) {
                s += __shfl_xor(s, 16); s += __shfl_xor(s, 32);
                q += __shfl_xor(q, 16); q += __shfl_xor(q, 32);
                if ((lane >> 4) == 0) {
                    atomicAdd(&lsum[c], s);
                    atomicAdd(&lsq[c], q);
                }
            }
        }
    }
    if (SOUT) {
        __syncthreads();
        float* cb = stats_out + (bid & (NCOPY - 1)) * 256;
        if (tid < 128) {
            atomicAdd(&cb[tid], lsum[tid]);
            atomicAdd(&cb[128 + tid], lsq[tid]);
        }
    }
}

// ---------------------------------------------------------------------------
// CSR build: bscan -> scanfix  (deg+eoff done in prew tail; no cursor)
// ---------------------------------------------------------------------------
__global__ __launch_bounds__(256) void bscan_kernel(
    const int* __restrict__ deg, int* __restrict__ rowptr, int* __restrict__ bsum)
{
    __shared__ int sm[256];
    const int t = threadIdx.x, idx = blockIdx.x * 256 + t;
    const int d = (idx < NN) ? deg[idx] : 0;
    sm[t] = d; __syncthreads();
    for (int ofs = 1; ofs < 256; ofs <<= 1) {
        int v = (t >= ofs) ? sm[t - ofs] : 0;
        __syncthreads();
        sm[t] += v;
        __syncthreads();
    }
    if (idx < NN) rowptr[idx] = sm[t] - d;  // exclusive, block-local
    if (t == 255) bsum[blockIdx.x] = sm[255];
}

__global__ __launch_bounds__(256) void scanfix_kernel(
    const int* __restrict__ bsum, int* __restrict__ rowptr)
{
    __shared__ int sm[256];
    const int t = threadIdx.x;
    const int d = (t < NB) ? bsum[t] : 0;
    sm[t] = d; __syncthreads();
    for (int ofs = 1; ofs < 256; ofs <<= 1) {
        int v = (t >= ofs) ? sm[t - ofs] : 0;
        __syncthreads();
        sm[t] += v;
        __syncthreads();
    }
    const int boff = (blockIdx.x == 0) ? 0 : sm[blockIdx.x - 1];
    const int idx = blockIdx.x * 256 + t;
    if (idx < NN) rowptr[idx] += boff;
    if (blockIdx.x == NB - 1 && t == 0) rowptr[NN] = sm[NB - 1];
}

// ---------------------------------------------------------------------------
// gather: z[n] = (1+eps[l])*f(src[n]) + sum_{c in adj[n]} f(src[c])
// 16 threads/node x 16B loads; 16 nodes per 256-thread block; 4-deep unroll.
// (r13 form: VGPR ~12, high occupancy — TLP beats ILP here, r14 lesson)
// ---------------------------------------------------------------------------
template <bool BN>
__global__ __launch_bounds__(256) void gather_kernel(
    const unsigned short* __restrict__ src, const int* __restrict__ rowptr,
    const int* __restrict__ adj, const float* __restrict__ stats,
    const float* __restrict__ gamma, const float* __restrict__ beta,
    const float* __restrict__ eps, int l, unsigned short* __restrict__ z)
{
    __shared__ float sarr[256];
    if constexpr (BN) {
        sarr[threadIdx.x] = fold_stat(stats, threadIdx.x);
        __syncthreads();
    }
    const int node = blockIdx.x * 16 + (threadIdx.x >> 4);
    const int c0 = (threadIdx.x & 15) * 8;
    if (node >= NN) return;
    float sc[8], sh[8];
    if (BN) {
#pragma unroll
        for (int j = 0; j < 8; j++) bn_ss(sarr, gamma, beta, c0 + j, sc[j], sh[j]);
    }
    const float e = 1.0f + eps[l];
    float acc[8];
    {
        mu32x4 v = *(const mu32x4*)(src + (size_t)node * HD + c0);
        const unsigned short* u = (const unsigned short*)&v;
#pragma unroll
        for (int j = 0; j < 8; j++) {
            float f = bf2f(u[j]);
            if (BN) f = fmaxf(f * sc[j] + sh[j], 0.f);
            acc[j] = e * f;
        }
    }
    const int s = rowptr[node], t = rowptr[node + 1];
    int i = s;
    for (; i + 4 <= t; i += 4) {
        const int n0 = adj[i], n1 = adj[i + 1], n2 = adj[i + 2], n3 = adj[i + 3];
        mu32x4 v0 = *(const mu32x4*)(src + (size_t)n0 * HD + c0);
        mu32x4 v1 = *(const mu32x4*)(src + (size_t)n1 * HD + c0);
        mu32x4 v2 = *(const mu32x4*)(src + (size_t)n2 * HD + c0);
        mu32x4 v3 = *(const mu32x4*)(src + (size_t)n3 * HD + c0);
        const unsigned short* u0 = (const unsigned short*)&v0;
        const unsigned short* u1 = (const unsigned short*)&v1;
        const unsigned short* u2 = (const unsigned short*)&v2;
        const unsigned short* u3 = (const unsigned short*)&v3;
#pragma unroll
        for (int j = 0; j < 8; j++) {
            float f0 = bf2f(u0[j]), f1 = bf2f(u1[j]);
            float f2 = bf2f(u2[j]), f3 = bf2f(u3[j]);
            if (BN) {
                f0 = fmaxf(f0 * sc[j] + sh[j], 0.f);
                f1 = fmaxf(f1 * sc[j] + sh[j], 0.f);
                f2 = fmaxf(f2 * sc[j] + sh[j], 0.f);
                f3 = fmaxf(f3 * sc[j] + sh[j], 0.f);
            }
            acc[j] += (f0 + f1) + (f2 + f3);
        }
    }
    for (; i < t; i++) {
        mu32x4 v = *(const mu32x4*)(src + (size_t)adj[i] * HD + c0);
        const unsigned short* u = (const unsigned short*)&v;
#pragma unroll
        for (int j = 0; j < 8; j++) {
            float f = bf2f(u[j]);
            if (BN) f = fmaxf(f * sc[j] + sh[j], 0.f);
            acc[j] += f;
        }
    }
    mu16x4 o0, o1;
#pragma unroll
    for (int j = 0; j < 4; j++) o0[j] = f2bf(acc[j]);
#pragma unroll
    for (int j = 0; j < 4; j++) o1[j] = f2bf(acc[4 + j]);
    *(mu16x4*)(z + (size_t)node * HD + c0) = o0;
    *(mu16x4*)(z + (size_t)node * HD + c0 + 4) = o1;
}

// ---------------------------------------------------------------------------
// pooled[g] = sum over graph rows of BN+ReLU(y); then out[g] = pooled @ pw + pb
// ---------------------------------------------------------------------------
__global__ __launch_bounds__(256) void poolfinal_kernel(
    const unsigned short* __restrict__ y, const int* __restrict__ start,
    const float* __restrict__ stats, const float* __restrict__ gamma,
    const float* __restrict__ beta, const float* __restrict__ pw,
    const float* __restrict__ pb, float* __restrict__ out)
{
    __shared__ float red[16][128];
    __shared__ float pl[128];
    __shared__ float sarr[256];
    sarr[threadIdx.x] = fold_stat(stats, threadIdx.x);
    __syncthreads();
    const int g = blockIdx.x;
    const int rg = threadIdx.x >> 4;
    const int c0 = (threadIdx.x & 15) * 8;
    float sc[8], sh[8];
#pragma unroll
    for (int j = 0; j < 8; j++) bn_ss(sarr, gamma, beta, c0 + j, sc[j], sh[j]);
    int s = start[g], e = start[g + 1];
    if (s < 0) s = 0;
    if (e > NN) e = NN;
    float acc[8];
#pragma unroll
    for (int j = 0; j < 8; j++) acc[j] = 0.f;
    for (int n = s + rg; n < e; n += 16) {
        mu32x4 v = *(const mu32x4*)(y + (size_t)n * HD + c0);
        const unsigned short* u = (const unsigned short*)&v;
#pragma unroll
        for (int j = 0; j < 8; j++)
            acc[j] += fmaxf(bf2f(u[j]) * sc[j] + sh[j], 0.f);
    }
#pragma unroll
    for (int j = 0; j < 8; j++) red[rg][c0 + j] = acc[j];
    __syncthreads();
    if (threadIdx.x < 128) {
        float a = 0.f;
#pragma unroll
        for (int k = 0; k < 16; k++) a += red[k][threadIdx.x];
        pl[threadIdx.x] = a;
    }
    __syncthreads();
    const int o = threadIdx.x;
    float facc = pb[o];
#pragma unroll 4
    for (int k = 0; k < 128; k++) facc += pl[k] * pw[k * 256 + o];
    out[(size_t)g * 256 + o] = facc;
}

// ---------------------------------------------------------------------------
extern "C" void kernel_launch(void* const* d_in, const int* in_sizes, int n_in,
                              void* d_out, int out_size, void* d_ws, size_t ws_size,
                              hipStream_t stream)
{
    const float* x      = (const float*)d_in[0];
    const int*   edge   = (const int*)d_in[1];
    const int*   batch  = (const int*)d_in[2];
    const float* emb_W  = (const float*)d_in[4];
    const float* emb_b  = (const float*)d_in[5];
    const float* W1     = (const float*)d_in[6];
    const float* b1     = (const float*)d_in[7];
    const float* g1     = (const float*)d_in[8];
    const float* be1    = (const float*)d_in[9];
    const float* W2     = (const float*)d_in[10];
    const float* b2     = (const float*)d_in[11];
    const float* g2     = (const float*)d_in[12];
    const float* be2    = (const float*)d_in[13];
    const float* eps    = (const float*)d_in[14];
    const float* proj_W = (const float*)d_in[15];
    const float* proj_b = (const float*)d_in[16];
    float* out = (float*)d_out;

    char* ws = (char*)d_ws;
    size_t off = 0;
    auto take = [&](size_t bytes) -> char* {
        char* p = ws + off;
        off += (bytes + 255) & ~(size_t)255;
        return p;
    };
    float*          stats  = (float*)take(6 * SREG * 4);   // 196 KB
    int*            start  = (int*)take((NG + 1) * 4);
    int*            deg    = (int*)take(NN * 4);
    int*            rowptr = (int*)take((NN + 1) * 4);
    int*            bsum   = (int*)take(256 * 4);
    unsigned short* wt     = (unsigned short*)take((size_t)(8192 + 6 * 16384) * 2);
    int*            adj    = (int*)take((size_t)NE * 4);
    int*            eoff   = (int*)take((size_t)NE * 4);
    unsigned short* zbuf   = (unsigned short*)take((size_t)NN * HD * 2);
    unsigned short* y1buf  = (unsigned short*)take((size_t)NN * HD * 2);
    unsigned short* y2buf  = (unsigned short*)take((size_t)NN * HD * 2);

    const int eg_grid = (NN + 63) / 64;    // 782 (embed, RG=1)
    const int lg_grid = (NN + 127) / 128;  // 391 (layer GEMMs, RG=2)
    auto st = [&](int r) { return stats + (size_t)r * SREG; };

    hipMemsetAsync(deg, 0, NN * 4, stream);
    // packed: wt convert + stats zero (416 blocks) || deg histogram + eoff (586)
    prew_kernel<<<PREWB + DEGB, 256, 0, stream>>>(
        emb_W, W1, W2, wt, stats, edge, deg, eoff);
    bscan_kernel<<<NB, 256, 0, stream>>>(deg, rowptr, bsum);
    scanfix_kernel<<<NB, 256, 0, stream>>>(bsum, rowptr);

    // packed: CSR fill, atomic-free (586 blocks) || embed GEMM (782, RG=1)
    gemm_kernel<AD, 1, 0, false, 1><<<FILLB + eg_grid, 256, 0, stream>>>(
        x, wt, emb_b, nullptr, nullptr, nullptr, y2buf, nullptr, NN,
        edge, rowptr, adj, eoff);

    for (int l = 0; l < 3; l++) {
        if (l == 0)
            gather_kernel<false><<<(NN + 15) / 16, 256, 0, stream>>>(
                y2buf, rowptr, adj, nullptr, nullptr, nullptr, eps, l, zbuf);
        else
            gather_kernel<true><<<(NN + 15) / 16, 256, 0, stream>>>(
                y2buf, rowptr, adj, st(2 * l - 1),
                g2 + (l - 1) * HD, be2 + (l - 1) * HD, eps, l, zbuf);
        gemm_kernel<HD, 2, 1, true, 0><<<lg_grid, 256, 0, stream>>>(
            zbuf, wt + 8192 + (size_t)l * 16384, b1 + l * HD,
            nullptr, nullptr, nullptr, y1buf, st(2 * l), NN,
            nullptr, nullptr, nullptr, nullptr);
        if (l < 2)
            gemm_kernel<HD, 2, 2, true, 0><<<lg_grid, 256, 0, stream>>>(
                y1buf, wt + 8192 + (size_t)(3 + l) * 16384, b2 + l * HD,
                st(2 * l), g1 + l * HD, be1 + l * HD, y2buf, st(2 * l + 1), NN,
                nullptr, nullptr, nullptr, nullptr);
        else
            // packed: graph starts (196 blocks) || last GEMM2 (391 blocks)
            gemm_kernel<HD, 2, 2, true, 2><<<NB + lg_grid, 256, 0, stream>>>(
                y1buf, wt + 8192 + (size_t)(3 + l) * 16384, b2 + l * HD,
                st(2 * l), g1 + l * HD, be1 + l * HD, y2buf, st(2 * l + 1), NN,
                batch, start, nullptr, nullptr);
    }

    poolfinal_kernel<<<NG, 256, 0, stream>>>(
        y2buf, start, st(5), g2 + 2 * HD, be2 + 2 * HD, proj_W, proj_b, out);
}

// Round 17
// 371.426 us; speedup vs baseline: 1.1716x; 1.0231x over previous
//
#include <hip/hip_runtime.h>
#include <stdint.h>

#define NN 50000   // nodes
#define NE 600000  // edges
#define NG 1000    // graphs
#define AD 64      // input feat
#define HD 128     // hidden
#define OD 256     // output
#define BN_EPS_F 1e-5f
#define INV_N (1.0f / 50000.0f)
#define NB 196     // scan blocks = ceil(NN/256)
#define FILLB 293  // fill tail blocks (8 edges/thread, pure stores)
#define DEGB 293   // degree tail blocks (8 edges/thread, eoff capture)
#define PREWB 416  // prew main blocks (wt convert = 106496 threads)
#define NCOPY 32   // stats spread copies (256 floats each)
#define SREG (NCOPY * 256)  // floats per stat region

typedef __attribute__((ext_vector_type(8))) short  mbf16x8;
typedef __attribute__((ext_vector_type(4))) float  mf32x4;
typedef __attribute__((ext_vector_type(4))) unsigned short mu16x4;
typedef __attribute__((ext_vector_type(4))) unsigned int   mu32x4;

union frag_cast { mu32x4 u; mbf16x8 b; mu16x4 h[2]; };

__device__ __forceinline__ float bf2f(unsigned short u) {
    union { unsigned int i; float f; } v; v.i = ((unsigned int)u) << 16; return v.f;
}
__device__ __forceinline__ unsigned short f2bf(float f) {
    union { float f; unsigned int i; } v; v.f = f;
    unsigned int r = v.i + 0x7fffu + ((v.i >> 16) & 1u);  // RNE
    return (unsigned short)(r >> 16);
}
// BN (scale, shift) for column c from folded raw sums
__device__ __forceinline__ void bn_ss(
    const float* stats, const float* __restrict__ gamma,
    const float* __restrict__ beta, int c, float& sc, float& sh)
{
    const float mean = stats[c] * INV_N;
    const float var = fmaxf(stats[128 + c] * INV_N - mean * mean, 0.f);
    const float inv = rsqrtf(var + BN_EPS_F);
    sc = gamma[c] * inv;
    sh = beta[c] - mean * sc;
}
// fold 32 spread copies of stat index t (t < 256) from a region
__device__ __forceinline__ float fold_stat(const float* __restrict__ reg, int t)
{
    float a = 0.f;
#pragma unroll
    for (int c = 0; c < NCOPY; c++) a += reg[c * 256 + t];
    return a;
}

// ---------------------------------------------------------------------------
// prew: wt[n][k] bf16 from W[k][n] fp32 (PREWB blocks) + zero stats.
// Tail blocks (DEGB, 8 edges/thread): degree histogram capturing each
// edge's within-row slot (eoff[e]) so the fill pass needs NO atomics.
// ---------------------------------------------------------------------------
__global__ __launch_bounds__(256) void prew_kernel(
    const float* __restrict__ emb_W, const float* __restrict__ W1,
    const float* __restrict__ W2, unsigned short* __restrict__ wt,
    float* __restrict__ stats, const int* __restrict__ ei,
    int* __restrict__ deg, int* __restrict__ eoff)
{
    if ((int)blockIdx.x >= PREWB) {
        const int e0 = ((blockIdx.x - PREWB) * 256 + threadIdx.x) * 8;
        if (e0 < NE) {   // NE % 8 == 0
            const int4 r0 = *(const int4*)(ei + e0);
            const int4 r1 = *(const int4*)(ei + e0 + 4);
            int4 o0 = {0, 0, 0, 0}, o1 = {0, 0, 0, 0};
            if ((unsigned)r0.x < NN) o0.x = atomicAdd(&deg[r0.x], 1);
            if ((unsigned)r0.y < NN) o0.y = atomicAdd(&deg[r0.y], 1);
            if ((unsigned)r0.z < NN) o0.z = atomicAdd(&deg[r0.z], 1);
            if ((unsigned)r0.w < NN) o0.w = atomicAdd(&deg[r0.w], 1);
            if ((unsigned)r1.x < NN) o1.x = atomicAdd(&deg[r1.x], 1);
            if ((unsigned)r1.y < NN) o1.y = atomicAdd(&deg[r1.y], 1);
            if ((unsigned)r1.z < NN) o1.z = atomicAdd(&deg[r1.z], 1);
            if ((unsigned)r1.w < NN) o1.w = atomicAdd(&deg[r1.w], 1);
            *(int4*)(eoff + e0) = o0;
            *(int4*)(eoff + e0 + 4) = o1;
        }
        return;
    }
    const int t = blockIdx.x * 256 + threadIdx.x;
    if (t < 6 * SREG) stats[t] = 0.f;
    if (t < 8192) {                    // emb: n=t>>6, k=t&63
        wt[t] = f2bf(emb_W[(t & 63) * 128 + (t >> 6)]);
    } else {
        const int t2 = t - 8192;
        if (t2 >= 6 * 16384) return;
        const int which = t2 >> 14, o = t2 & 16383;
        const int n = o >> 7, k = o & 127;
        const float* src = (which < 3) ? (W1 + (size_t)which * 16384)
                                       : (W2 + (size_t)(which - 3) * 16384);
        wt[t] = f2bf(src[k * 128 + n]);
    }
}

// ---------------------------------------------------------------------------
// GEMM: out_bf16[N,128] = A[N,K] @ Wt^T + bias
// AMODE 0: A fp32 -> LDS staging (embed; packed under fill)
// AMODE 1/2: A bf16 loaded DIRECTLY global->registers (A has no reuse).
// SOUT: per-column sum/sumsq -> spread copy (bid&31); consumers fold.
// TAIL: 1 = CSR fill tail (8 edges/thread, pure stores), 2 = graph-starts
// ---------------------------------------------------------------------------
template <int K, int RG, int AMODE, bool SOUT, int TAIL>
__global__ __launch_bounds__(256) void gemm_kernel(
    const void* __restrict__ in, const unsigned short* __restrict__ Wt,
    const float* __restrict__ bias, const float* __restrict__ stats_in,
    const float* __restrict__ gamma, const float* __restrict__ beta,
    unsigned short* __restrict__ out, float* __restrict__ stats_out, int n_rows,
    const int* __restrict__ t_a, int* __restrict__ t_b, int* __restrict__ t_c,
    const int* __restrict__ t_d)
{
    constexpr int TAILB = (TAIL == 1) ? FILLB : (TAIL == 2) ? NB : 0;
    if (TAIL != 0 && (int)blockIdx.x < TAILB) {
        const int t = blockIdx.x * 256 + threadIdx.x;
        if constexpr (TAIL == 1) {
            // t_a = edge, t_b = rowptr (read-only), t_c = adj, t_d = eoff
            const int e0 = t * 8;
            if (e0 < NE) {   // NE % 8 == 0
                const int4 r0 = *(const int4*)(t_a + e0);
                const int4 r1 = *(const int4*)(t_a + e0 + 4);
                const int4 c0 = *(const int4*)(t_a + NE + e0);
                const int4 c1 = *(const int4*)(t_a + NE + e0 + 4);
                const int4 o0 = *(const int4*)(t_d + e0);
                const int4 o1 = *(const int4*)(t_d + e0 + 4);
                if ((unsigned)r0.x < NN && (unsigned)c0.x < NN)
                    t_c[t_b[r0.x] + o0.x] = c0.x;
                if ((unsigned)r0.y < NN && (unsigned)c0.y < NN)
                    t_c[t_b[r0.y] + o0.y] = c0.y;
                if ((unsigned)r0.z < NN && (unsigned)c0.z < NN)
                    t_c[t_b[r0.z] + o0.z] = c0.z;
                if ((unsigned)r0.w < NN && (unsigned)c0.w < NN)
                    t_c[t_b[r0.w] + o0.w] = c0.w;
                if ((unsigned)r1.x < NN && (unsigned)c1.x < NN)
                    t_c[t_b[r1.x] + o1.x] = c1.x;
                if ((unsigned)r1.y < NN && (unsigned)c1.y < NN)
                    t_c[t_b[r1.y] + o1.y] = c1.y;
                if ((unsigned)r1.z < NN && (unsigned)c1.z < NN)
                    t_c[t_b[r1.z] + o1.z] = c1.z;
                if ((unsigned)r1.w < NN && (unsigned)c1.w < NN)
                    t_c[t_b[r1.w] + o1.w] = c1.w;
            }
        } else {  // TAIL == 2: graph starts
            if (t < NN) {
                int b = t_a[t];
                int pb = (t == 0) ? -1 : t_a[t - 1];
                if (b > NG - 1) b = NG - 1;
                if (pb > NG - 1) pb = NG - 1;
                for (int g = pb + 1; g <= b; g++) t_b[g] = t;
                if (t == NN - 1)
                    for (int g = b + 1; g <= NG; g++) t_b[g] = NN;
            }
        }
        return;
    }
    const int bid = blockIdx.x - TAILB;

    constexpr int ROWS = RG * 64;
    constexpr int SA = K + 8;
    constexpr int ZN = (AMODE == 0) ? ROWS * SA : 1;
    __shared__ unsigned short zs[ZN];
    __shared__ float ssl[128], ssh[128];
    __shared__ float lsum[128], lsq[128];
    __shared__ float sarr[256];

    const int tid = threadIdx.x;
    const int wave = tid >> 6, lane = tid & 63;
    const int row0 = bid * ROWS;

    if (SOUT && tid < 128) { lsum[tid] = 0.f; lsq[tid] = 0.f; }
    if (AMODE == 2) {
        sarr[tid] = fold_stat(stats_in, tid);
        __syncthreads();
        if (tid < 128) {
            float sc, sh; bn_ss(sarr, gamma, beta, tid, sc, sh);
            ssl[tid] = sc; ssh[tid] = sh;
        }
        __syncthreads();
    }

    // ---- AMODE 0 only: stage fp32 A tile -> LDS ----
    if constexpr (AMODE == 0) {
        const float* src = (const float*)in;
        constexpr int LPR = K / 4;
        for (int i = tid; i < ROWS * LPR; i += 256) {
            const int r = i / LPR, c4 = (i % LPR) * 4;
            mf32x4 v = {0.f, 0.f, 0.f, 0.f};
            if (row0 + r < n_rows)
                v = *(const mf32x4*)(src + (size_t)(row0 + r) * K + c4);
            mu16x4 o;
            o[0] = f2bf(v[0]); o[1] = f2bf(v[1]); o[2] = f2bf(v[2]); o[3] = f2bf(v[3]);
            *(mu16x4*)(&zs[r * SA + c4]) = o;
        }
        __syncthreads();
    }

    // ---- MFMA: B-frags from global; A-frags from LDS (0) or global (1/2) ----
    mf32x4 acc[RG][8];
#pragma unroll
    for (int g = 0; g < RG; g++)
#pragma unroll
        for (int t = 0; t < 8; t++) acc[g][t] = {0.f, 0.f, 0.f, 0.f};
    const int kq = (lane >> 4) * 8;
    int mrow[RG];
#pragma unroll
    for (int g = 0; g < RG; g++) mrow[g] = wave * (16 * RG) + g * 16 + (lane & 15);
    const unsigned short* asrc = (const unsigned short*)in;
    const unsigned short* wn = Wt + (lane & 15) * K;  // + t*16*K + k0
#pragma unroll 1
    for (int kk = 0; kk < K / 32; kk++) {
        const int k0 = kk * 32 + kq;
        mbf16x8 a[RG];
        if constexpr (AMODE == 0) {
#pragma unroll
            for (int g = 0; g < RG; g++)
                a[g] = *(const mbf16x8*)(&zs[mrow[g] * SA + k0]);
        } else {
#pragma unroll
            for (int g = 0; g < RG; g++) {
                frag_cast fc;
                fc.u = (mu32x4){0, 0, 0, 0};
                const int grow = row0 + mrow[g];
                if (grow < n_rows)
                    fc.u = *(const mu32x4*)(asrc + (size_t)grow * K + k0);
                if constexpr (AMODE == 2) {
                    const mf32x4 sc0 = *(const mf32x4*)(ssl + k0);
                    const mf32x4 sc1 = *(const mf32x4*)(ssl + k0 + 4);
                    const mf32x4 sh0 = *(const mf32x4*)(ssh + k0);
                    const mf32x4 sh1 = *(const mf32x4*)(ssh + k0 + 4);
                    const unsigned short* u = (const unsigned short*)&fc.u;
                    mu16x4 pa, pb2;
#pragma unroll
                    for (int j = 0; j < 4; j++)
                        pa[j] = f2bf(fmaxf(bf2f(u[j]) * sc0[j] + sh0[j], 0.f));
#pragma unroll
                    for (int j = 0; j < 4; j++)
                        pb2[j] = f2bf(fmaxf(bf2f(u[4 + j]) * sc1[j] + sh1[j], 0.f));
                    fc.h[0] = pa; fc.h[1] = pb2;
                }
                a[g] = fc.b;
            }
        }
        mbf16x8 bfr[8];
#pragma unroll
        for (int t = 0; t < 8; t++) bfr[t] = *(const mbf16x8*)(wn + t * 16 * K + k0);
#pragma unroll
        for (int t = 0; t < 8; t++)
#pragma unroll
            for (int g = 0; g < RG; g++)
                acc[g][t] = __builtin_amdgcn_mfma_f32_16x16x32_bf16(
                    a[g], bfr[t], acc[g][t], 0, 0, 0);
    }

    // ---- epilogue: +bias, store bf16; stats -> spread copy (bid&31) ----
#pragma unroll
    for (int g = 0; g < RG; g++) {
        const int rbase = wave * (16 * RG) + g * 16 + ((lane >> 4) << 2);
#pragma unroll
        for (int t = 0; t < 8; t++) {
            const int c = t * 16 + (lane & 15);
            const float bv = bias[c];
            float s = 0.f, q = 0.f;
#pragma unroll
            for (int r = 0; r < 4; r++) {
                const int grow = row0 + rbase + r;
                const float y = acc[g][t][r] + bv;
                if (grow < n_rows) {
                    out[(size_t)grow * 128 + c] = f2bf(y);
                    if (SOUT) { s += y; q += y * y; }
                }
            }
            if (SOUT) {
                s += __shfl_xor(s, 16); s += __shfl_xor(s, 32);
                q += __shfl_xor(q, 16); q += __shfl_xor(q, 32);
                if ((lane >> 4) == 0) {
                    atomicAdd(&lsum[c], s);
                    atomicAdd(&lsq[c], q);
                }
            }
        }
    }
    if (SOUT) {
        __syncthreads();
        float* cb = stats_out + (bid & (NCOPY - 1)) * 256;
        if (tid < 128) {
            atomicAdd(&cb[tid], lsum[tid]);
            atomicAdd(&cb[128 + tid], lsq[tid]);
        }
    }
}

// ---------------------------------------------------------------------------
// CSR build: bscan -> scanfix  (deg+eoff done in prew tail; no cursor)
// ---------------------------------------------------------------------------
__global__ __launch_bounds__(256) void bscan_kernel(
    const int* __restrict__ deg, int* __restrict__ rowptr, int* __restrict__ bsum)
{
    __shared__ int sm[256];
    const int t = threadIdx.x, idx = blockIdx.x * 256 + t;
    const int d = (idx < NN) ? deg[idx] : 0;
    sm[t] = d; __syncthreads();
    for (int ofs = 1; ofs < 256; ofs <<= 1) {
        int v = (t >= ofs) ? sm[t - ofs] : 0;
        __syncthreads();
        sm[t] += v;
        __syncthreads();
    }
    if (idx < NN) rowptr[idx] = sm[t] - d;  // exclusive, block-local
    if (t == 255) bsum[blockIdx.x] = sm[255];
}

__global__ __launch_bounds__(256) void scanfix_kernel(
    const int* __restrict__ bsum, int* __restrict__ rowptr)
{
    __shared__ int sm[256];
    const int t = threadIdx.x;
    const int d = (t < NB) ? bsum[t] : 0;
    sm[t] = d; __syncthreads();
    for (int ofs = 1; ofs < 256; ofs <<= 1) {
        int v = (t >= ofs) ? sm[t - ofs] : 0;
        __syncthreads();
        sm[t] += v;
        __syncthreads();
    }
    const int boff = (blockIdx.x == 0) ? 0 : sm[blockIdx.x - 1];
    const int idx = blockIdx.x * 256 + t;
    if (idx < NN) rowptr[idx] += boff;
    if (blockIdx.x == NB - 1 && t == 0) rowptr[NN] = sm[NB - 1];
}

// ---------------------------------------------------------------------------
// gather: z[n] = (1+eps[l])*f(src[n]) + sum_{c in adj[n]} f(src[c])
// 16 threads/node x 16B loads; 16 nodes per 256-thread block; 4-deep row
// loads with NEXT-iteration adj indices prefetched while rows are in flight.
// ---------------------------------------------------------------------------
template <bool BN>
__global__ __launch_bounds__(256) void gather_kernel(
    const unsigned short* __restrict__ src, const int* __restrict__ rowptr,
    const int* __restrict__ adj, const float* __restrict__ stats,
    const float* __restrict__ gamma, const float* __restrict__ beta,
    const float* __restrict__ eps, int l, unsigned short* __restrict__ z)
{
    __shared__ float sarr[256];
    if constexpr (BN) {
        sarr[threadIdx.x] = fold_stat(stats, threadIdx.x);
        __syncthreads();
    }
    const int node = blockIdx.x * 16 + (threadIdx.x >> 4);  // NN % 16 == 0
    const int c0 = (threadIdx.x & 15) * 8;
    float sc[8], sh[8];
    if (BN) {
#pragma unroll
        for (int j = 0; j < 8; j++) bn_ss(sarr, gamma, beta, c0 + j, sc[j], sh[j]);
    }
    const float e = 1.0f + eps[l];
    float acc[8];
    {
        mu32x4 v = *(const mu32x4*)(src + (size_t)node * HD + c0);
        const unsigned short* u = (const unsigned short*)&v;
#pragma unroll
        for (int j = 0; j < 8; j++) {
            float f = bf2f(u[j]);
            if (BN) f = fmaxf(f * sc[j] + sh[j], 0.f);
            acc[j] = e * f;
        }
    }
    const int s = rowptr[node], t = rowptr[node + 1];
    int i = s;
    int n0 = 0, n1 = 0, n2 = 0, n3 = 0;
    if (i + 4 <= t) { n0 = adj[i]; n1 = adj[i + 1]; n2 = adj[i + 2]; n3 = adj[i + 3]; }
    while (i + 4 <= t) {
        mu32x4 v0 = *(const mu32x4*)(src + (size_t)n0 * HD + c0);
        mu32x4 v1 = *(const mu32x4*)(src + (size_t)n1 * HD + c0);
        mu32x4 v2 = *(const mu32x4*)(src + (size_t)n2 * HD + c0);
        mu32x4 v3 = *(const mu32x4*)(src + (size_t)n3 * HD + c0);
        i += 4;
        if (i + 4 <= t) {  // prefetch next indices while v0..v3 in flight
            n0 = adj[i]; n1 = adj[i + 1]; n2 = adj[i + 2]; n3 = adj[i + 3];
        }
        const unsigned short* u0 = (const unsigned short*)&v0;
        const unsigned short* u1 = (const unsigned short*)&v1;
        const unsigned short* u2 = (const unsigned short*)&v2;
        const unsigned short* u3 = (const unsigned short*)&v3;
#pragma unroll
        for (int j = 0; j < 8; j++) {
            float f0 = bf2f(u0[j]), f1 = bf2f(u1[j]);
            float f2 = bf2f(u2[j]), f3 = bf2f(u3[j]);
            if (BN) {
                f0 = fmaxf(f0 * sc[j] + sh[j], 0.f);
                f1 = fmaxf(f1 * sc[j] + sh[j], 0.f);
                f2 = fmaxf(f2 * sc[j] + sh[j], 0.f);
                f3 = fmaxf(f3 * sc[j] + sh[j], 0.f);
            }
            acc[j] += (f0 + f1) + (f2 + f3);
        }
    }
    for (; i < t; i++) {
        mu32x4 v = *(const mu32x4*)(src + (size_t)adj[i] * HD + c0);
        const unsigned short* u = (const unsigned short*)&v;
#pragma unroll
        for (int j = 0; j < 8; j++) {
            float f = bf2f(u[j]);
            if (BN) f = fmaxf(f * sc[j] + sh[j], 0.f);
            acc[j] += f;
        }
    }
    mu16x4 o0, o1;
#pragma unroll
    for (int j = 0; j < 4; j++) o0[j] = f2bf(acc[j]);
#pragma unroll
    for (int j = 0; j < 4; j++) o1[j] = f2bf(acc[4 + j]);
    *(mu16x4*)(z + (size_t)node * HD + c0) = o0;
    *(mu16x4*)(z + (size_t)node * HD + c0 + 4) = o1;
}

// ---------------------------------------------------------------------------
// pooled[g] = sum over graph rows of BN+ReLU(y); then out[g] = pooled @ pw + pb
// ---------------------------------------------------------------------------
__global__ __launch_bounds__(256) void poolfinal_kernel(
    const unsigned short* __restrict__ y, const int* __restrict__ start,
    const float* __restrict__ stats, const float* __restrict__ gamma,
    const float* __restrict__ beta, const float* __restrict__ pw,
    const float* __restrict__ pb, float* __restrict__ out)
{
    __shared__ float red[16][128];
    __shared__ float pl[128];
    __shared__ float sarr[256];
    sarr[threadIdx.x] = fold_stat(stats, threadIdx.x);
    __syncthreads();
    const int g = blockIdx.x;
    const int rg = threadIdx.x >> 4;
    const int c0 = (threadIdx.x & 15) * 8;
    float sc[8], sh[8];
#pragma unroll
    for (int j = 0; j < 8; j++) bn_ss(sarr, gamma, beta, c0 + j, sc[j], sh[j]);
    int s = start[g], e = start[g + 1];
    if (s < 0) s = 0;
    if (e > NN) e = NN;
    float acc[8];
#pragma unroll
    for (int j = 0; j < 8; j++) acc[j] = 0.f;
    for (int n = s + rg; n < e; n += 16) {
        mu32x4 v = *(const mu32x4*)(y + (size_t)n * HD + c0);
        const unsigned short* u = (const unsigned short*)&v;
#pragma unroll
        for (int j = 0; j < 8; j++)
            acc[j] += fmaxf(bf2f(u[j]) * sc[j] + sh[j], 0.f);
    }
#pragma unroll
    for (int j = 0; j < 8; j++) red[rg][c0 + j] = acc[j];
    __syncthreads();
    if (threadIdx.x < 128) {
        float a = 0.f;
#pragma unroll
        for (int k = 0; k < 16; k++) a += red[k][threadIdx.x];
        pl[threadIdx.x] = a;
    }
    __syncthreads();
    const int o = threadIdx.x;
    float facc = pb[o];
#pragma unroll 4
    for (int k = 0; k < 128; k++) facc += pl[k] * pw[k * 256 + o];
    out[(size_t)g * 256 + o] = facc;
}

// ---------------------------------------------------------------------------
extern "C" void kernel_launch(void* const* d_in, const int* in_sizes, int n_in,
                              void* d_out, int out_size, void* d_ws, size_t ws_size,
                              hipStream_t stream)
{
    const float* x      = (const float*)d_in[0];
    const int*   edge   = (const int*)d_in[1];
    const int*   batch  = (const int*)d_in[2];
    const float* emb_W  = (const float*)d_in[4];
    const float* emb_b  = (const float*)d_in[5];
    const float* W1     = (const float*)d_in[6];
    const float* b1     = (const float*)d_in[7];
    const float* g1     = (const float*)d_in[8];
    const float* be1    = (const float*)d_in[9];
    const float* W2     = (const float*)d_in[10];
    const float* b2     = (const float*)d_in[11];
    const float* g2     = (const float*)d_in[12];
    const float* be2    = (const float*)d_in[13];
    const float* eps    = (const float*)d_in[14];
    const float* proj_W = (const float*)d_in[15];
    const float* proj_b = (const float*)d_in[16];
    float* out = (float*)d_out;

    char* ws = (char*)d_ws;
    size_t off = 0;
    auto take = [&](size_t bytes) -> char* {
        char* p = ws + off;
        off += (bytes + 255) & ~(size_t)255;
        return p;
    };
    float*          stats  = (float*)take(6 * SREG * 4);   // 196 KB
    int*            start  = (int*)take((NG + 1) * 4);
    int*            deg    = (int*)take(NN * 4);
    int*            rowptr = (int*)take((NN + 1) * 4);
    int*            bsum   = (int*)take(256 * 4);
    unsigned short* wt     = (unsigned short*)take((size_t)(8192 + 6 * 16384) * 2);
    int*            adj    = (int*)take((size_t)NE * 4);
    int*            eoff   = (int*)take((size_t)NE * 4);
    unsigned short* zbuf   = (unsigned short*)take((size_t)NN * HD * 2);
    unsigned short* y1buf  = (unsigned short*)take((size_t)NN * HD * 2);
    unsigned short* y2buf  = (unsigned short*)take((size_t)NN * HD * 2);

    const int eg_grid = (NN + 63) / 64;    // 782 (embed, RG=1)
    const int lg_grid = (NN + 127) / 128;  // 391 (layer GEMMs, RG=2)
    auto st = [&](int r) { return stats + (size_t)r * SREG; };

    hipMemsetAsync(deg, 0, NN * 4, stream);
    // packed: wt convert + stats zero (416 blocks) || deg histogram + eoff (293)
    prew_kernel<<<PREWB + DEGB, 256, 0, stream>>>(
        emb_W, W1, W2, wt, stats, edge, deg, eoff);
    bscan_kernel<<<NB, 256, 0, stream>>>(deg, rowptr, bsum);
    scanfix_kernel<<<NB, 256, 0, stream>>>(bsum, rowptr);

    // packed: CSR fill, atomic-free (293 blocks) || embed GEMM (782, RG=1)
    gemm_kernel<AD, 1, 0, false, 1><<<FILLB + eg_grid, 256, 0, stream>>>(
        x, wt, emb_b, nullptr, nullptr, nullptr, y2buf, nullptr, NN,
        edge, rowptr, adj, eoff);

    for (int l = 0; l < 3; l++) {
        if (l == 0)
            gather_kernel<false><<<(NN + 15) / 16, 256, 0, stream>>>(
                y2buf, rowptr, adj, nullptr, nullptr, nullptr, eps, l, zbuf);
        else
            gather_kernel<true><<<(NN + 15) / 16, 256, 0, stream>>>(
                y2buf, rowptr, adj, st(2 * l - 1),
                g2 + (l - 1) * HD, be2 + (l - 1) * HD, eps, l, zbuf);
        gemm_kernel<HD, 2, 1, true, 0><<<lg_grid, 256, 0, stream>>>(
            zbuf, wt + 8192 + (size_t)l * 16384, b1 + l * HD,
            nullptr, nullptr, nullptr, y1buf, st(2 * l), NN,
            nullptr, nullptr, nullptr, nullptr);
        if (l < 2)
            gemm_kernel<HD, 2, 2, true, 0><<<lg_grid, 256, 0, stream>>>(
                y1buf, wt + 8192 + (size_t)(3 + l) * 16384, b2 + l * HD,
                st(2 * l), g1 + l * HD, be1 + l * HD, y2buf, st(2 * l + 1), NN,
                nullptr, nullptr, nullptr, nullptr);
        else
            // packed: graph starts (196 blocks) || last GEMM2 (391 blocks)
            gemm_kernel<HD, 2, 2, true, 2><<<NB + lg_grid, 256, 0, stream>>>(
                y1buf, wt + 8192 + (size_t)(3 + l) * 16384, b2 + l * HD,
                st(2 * l), g1 + l * HD, be1 + l * HD, y2buf, st(2 * l + 1), NN,
                batch, start, nullptr, nullptr);
    }

    poolfinal_kernel<<<NG, 256, 0, stream>>>(
        y2buf, start, st(5), g2 + 2 * HD, be2 + 2 * HD, proj_W, proj_b, out);
}